// Round 1
// baseline (1444.448 us; speedup 1.0000x reference)
//
#include <hip/hip_runtime.h>

#define HD 128          // hidden dim (== DIN)
#define DDOC 512
#define TOUT 32
constexpr float NEG_SLOPE = 0.2f;

// ---------- helpers ----------
__device__ __forceinline__ int enc_f32(float f) {
    int b = __float_as_int(f);
    return b >= 0 ? b : (b ^ 0x7fffffff);
}
__device__ __forceinline__ float dec_f32(int b) {
    return __int_as_float(b >= 0 ? b : (b ^ 0x7fffffff));
}

// ---------- zero / init ----------
__global__ void k_zero(float* __restrict__ p, int n) {
    int i = blockIdx.x * blockDim.x + threadIdx.x;
    if (i < n) p[i] = 0.f;
}
__global__ void k_init_seg(int* __restrict__ m_int, float* __restrict__ denom, int n) {
    int i = blockIdx.x * blockDim.x + threadIdx.x;
    if (i < n) { m_int[i] = 0x80000000; denom[i] = 0.f; }
}

// ---------- h = x @ W ; alpha_src/dst = h . a ----------
__global__ void k_gemm_alpha(const float* __restrict__ x, const float* __restrict__ W,
                             const float* __restrict__ av_s, const float* __restrict__ av_d,
                             float* __restrict__ h, float* __restrict__ alp_s,
                             float* __restrict__ alp_d, int n) {
    int row = blockIdx.x;
    if (row >= n) return;
    int t = threadIdx.x;           // 0..127
    __shared__ float xs[HD];
    xs[t] = x[row * HD + t];
    __syncthreads();
    float acc = 0.f;
#pragma unroll
    for (int k = 0; k < HD; ++k) acc += xs[k] * W[k * HD + t];
    h[row * HD + t] = acc;

    float vs = acc * av_s[t];
    float vd = acc * av_d[t];
#pragma unroll
    for (int off = 32; off > 0; off >>= 1) {
        vs += __shfl_down(vs, off);
        vd += __shfl_down(vd, off);
    }
    __shared__ float red[4];
    if ((t & 63) == 0) { red[t >> 6] = vs; red[2 + (t >> 6)] = vd; }
    __syncthreads();
    if (t == 0) { alp_s[row] = red[0] + red[1]; alp_d[row] = red[2] + red[3]; }
}

// ---------- edge pass 1: e = leaky_relu(as[s]+ad[d]); segment max ----------
__global__ void k_edge_max(const int* __restrict__ ei, int E, int Etot,
                           const float* __restrict__ alp_s, const float* __restrict__ alp_d,
                           float* __restrict__ ebuf, int* __restrict__ m_int) {
    int i = blockIdx.x * blockDim.x + threadIdx.x;
    if (i >= Etot) return;
    int s, d;
    if (i < E) { s = ei[i]; d = ei[E + i]; } else { s = d = i - E; }
    float e = alp_s[s] + alp_d[d];
    e = e > 0.f ? e : NEG_SLOPE * e;
    ebuf[i] = e;
    atomicMax(&m_int[d], enc_f32(e));
}

// ---------- edge pass 2: ee = exp(e - m[d]); denom[d] += ee ----------
__global__ void k_edge_exp(const int* __restrict__ ei, int E, int Etot,
                           float* __restrict__ ebuf, const int* __restrict__ m_int,
                           float* __restrict__ denom) {
    int i = blockIdx.x * blockDim.x + threadIdx.x;
    if (i >= Etot) return;
    int d = (i < E) ? ei[E + i] : (i - E);
    float m = dec_f32(m_int[d]);
    float ee = expf(ebuf[i] - m);
    ebuf[i] = ee;
    atomicAdd(&denom[d], ee);
}

// ---------- edge pass 3: out[d] += h[s] * (ee/denom[d]) ----------
__global__ void k_scatter(const int* __restrict__ ei, int E, int Etot,
                          const float* __restrict__ h, const float* __restrict__ ebuf,
                          const float* __restrict__ denom, float* __restrict__ out) {
    int e = blockIdx.x;
    if (e >= Etot) return;
    int t = threadIdx.x;           // 0..127
    int s, d;
    if (e < E) { s = ei[e]; d = ei[E + e]; } else { s = d = e - E; }
    float alpha = ebuf[e] / denom[d];
    atomicAdd(&out[d * HD + t], h[s * HD + t] * alpha);
}

// ---------- bias + relu ----------
__global__ void k_bias_relu(float* __restrict__ x, const float* __restrict__ b, int total) {
    int i = blockIdx.x * blockDim.x + threadIdx.x;
    if (i >= total) return;
    float v = x[i] + b[i & (HD - 1)];
    x[i] = v > 0.f ? v : 0.f;
}

// ---------- pooling ----------
__global__ void k_count(const int* __restrict__ batch, float* __restrict__ counts, int n) {
    int i = blockIdx.x * blockDim.x + threadIdx.x;
    if (i < n) atomicAdd(&counts[batch[i]], 1.0f);
}
__global__ void k_pool(const float* __restrict__ x, const int* __restrict__ batch,
                       float* __restrict__ pooled, int n) {
    int i = blockIdx.x;
    if (i >= n) return;
    int t = threadIdx.x;
    atomicAdd(&pooled[batch[i] * HD + t], x[i * HD + t]);
}

// ---------- doc embedding: relu(doc @ W_doc + b_doc) ----------
__global__ void k_doc(const float* __restrict__ doc, const float* __restrict__ Wd,
                      const float* __restrict__ bd, float* __restrict__ emb) {
    int g = blockIdx.x;
    int t = threadIdx.x;           // 0..127
    __shared__ float ds[DDOC];
    for (int k = t; k < DDOC; k += HD) ds[k] = doc[g * DDOC + k];
    __syncthreads();
    float acc = bd[t];
    for (int k = 0; k < DDOC; ++k) acc += ds[k] * Wd[k * HD + t];
    emb[g * HD + t] = acc > 0.f ? acc : 0.f;
}

// ---------- heads ----------
__global__ void k_head(const float* __restrict__ pooled, const float* __restrict__ counts,
                       const float* __restrict__ emb,
                       const float* __restrict__ Wt, const float* __restrict__ bt,
                       const float* __restrict__ Wm, const float* __restrict__ bm,
                       float* __restrict__ out_task, float* __restrict__ out_time) {
    int g = blockIdx.x;
    int t = threadIdx.x;           // 0..63
    __shared__ float z[2 * HD];
    float cnt = counts[g];
    cnt = cnt < 1.f ? 1.f : cnt;
    for (int k = t; k < HD; k += 64) {
        z[k] = pooled[g * HD + k] / cnt;
        z[HD + k] = emb[g * HD + k];
    }
    __syncthreads();
    if (t < TOUT) {
        float acc = bt[t];
        for (int k = 0; k < 2 * HD; ++k) acc += z[k] * Wt[k * TOUT + t];
        out_task[g * TOUT + t] = acc;
    } else if (t == TOUT) {
        float acc = bm[0];
        for (int k = 0; k < 2 * HD; ++k) acc += z[k] * Wm[k];
        out_time[g] = acc;
    }
}

extern "C" void kernel_launch(void* const* d_in, const int* in_sizes, int n_in,
                              void* d_out, int out_size, void* d_ws, size_t ws_size,
                              hipStream_t stream) {
    const float* x0    = (const float*)d_in[0];
    const int*   ei    = (const int*)d_in[1];
    const int*   batch = (const int*)d_in[2];
    const float* doc   = (const float*)d_in[3];
    const float* W[3]   = {(const float*)d_in[4],  (const float*)d_in[8],  (const float*)d_in[12]};
    const float* a_s[3] = {(const float*)d_in[5],  (const float*)d_in[9],  (const float*)d_in[13]};
    const float* a_d[3] = {(const float*)d_in[6],  (const float*)d_in[10], (const float*)d_in[14]};
    const float* b[3]   = {(const float*)d_in[7],  (const float*)d_in[11], (const float*)d_in[15]};
    const float* Wdoc  = (const float*)d_in[16];
    const float* bdoc  = (const float*)d_in[17];
    const float* Wtask = (const float*)d_in[18];
    const float* btask = (const float*)d_in[19];
    const float* Wtime = (const float*)d_in[20];
    const float* btime = (const float*)d_in[21];

    const int N    = in_sizes[2];
    const int E    = in_sizes[1] / 2;
    const int Etot = E + N;
    const int G    = in_sizes[3] / DDOC;

    // workspace layout
    float* ws = (float*)d_ws;
    float* A      = ws; ws += (size_t)N * HD;   // node features / aggregation buffer
    float* Hb     = ws; ws += (size_t)N * HD;   // h = x @ W
    float* ebuf   = ws; ws += Etot;             // per-edge e then exp(e-m)
    float* alp_s  = ws; ws += N;
    float* alp_d  = ws; ws += N;
    float* denom  = ws; ws += N;
    int*   m_int  = (int*)ws; ws += N;
    float* pooled = ws; ws += (size_t)G * HD;
    float* counts = ws; ws += G;
    float* emb    = ws; ws += (size_t)G * HD;

    float* out_task = (float*)d_out;
    float* out_time = out_task + (size_t)G * TOUT;

    const int thr = 256;
    const int nhBlocks = (N * HD + thr - 1) / thr;
    const int nBlocks  = (N + thr - 1) / thr;
    const int eBlocks  = (Etot + thr - 1) / thr;

    const float* xin = x0;
    for (int l = 0; l < 3; ++l) {
        k_gemm_alpha<<<N, HD, 0, stream>>>(xin, W[l], a_s[l], a_d[l], Hb, alp_s, alp_d, N);
        k_init_seg<<<nBlocks, thr, 0, stream>>>(m_int, denom, N);
        k_zero<<<nhBlocks, thr, 0, stream>>>(A, N * HD);
        k_edge_max<<<eBlocks, thr, 0, stream>>>(ei, E, Etot, alp_s, alp_d, ebuf, m_int);
        k_edge_exp<<<eBlocks, thr, 0, stream>>>(ei, E, Etot, ebuf, m_int, denom);
        k_scatter<<<Etot, HD, 0, stream>>>(ei, E, Etot, Hb, ebuf, denom, A);
        k_bias_relu<<<nhBlocks, thr, 0, stream>>>(A, b[l], N * HD);
        xin = A;
    }

    // global mean pool
    k_zero<<<(G * HD + thr - 1) / thr, thr, 0, stream>>>(pooled, G * HD);
    k_zero<<<1, thr, 0, stream>>>(counts, G);
    k_count<<<nBlocks, thr, 0, stream>>>(batch, counts, N);
    k_pool<<<N, HD, 0, stream>>>(A, batch, pooled, N);

    // doc embedding + heads
    k_doc<<<G, HD, 0, stream>>>(doc, Wdoc, bdoc, emb);
    k_head<<<G, 64, 0, stream>>>(pooled, counts, emb, Wtask, btask, Wtime, btime,
                                 out_task, out_time);
}

// Round 2
// 708.722 us; speedup vs baseline: 2.0381x; 2.0381x over previous
//
#include <hip/hip_runtime.h>

#define HD 128          // hidden dim (== DIN)
#define DDOC 512
#define TOUT 32
constexpr float NEG_SLOPE = 0.2f;

// ---------- zero ----------
__global__ void k_zero(float* __restrict__ p, int n) {
    int i = blockIdx.x * blockDim.x + threadIdx.x;
    if (i < n) p[i] = 0.f;
}
__global__ void k_zero_int(int* __restrict__ p, int n) {
    int i = blockIdx.x * blockDim.x + threadIdx.x;
    if (i < n) p[i] = 0;
}

// ---------- h = x @ W ; alpha_src/dst = h . a ----------
__global__ void k_gemm_alpha(const float* __restrict__ x, const float* __restrict__ W,
                             const float* __restrict__ av_s, const float* __restrict__ av_d,
                             float* __restrict__ h, float* __restrict__ alp_s,
                             float* __restrict__ alp_d, int n) {
    int row = blockIdx.x;
    if (row >= n) return;
    int t = threadIdx.x;           // 0..127
    __shared__ float xs[HD];
    xs[t] = x[row * HD + t];
    __syncthreads();
    float acc = 0.f;
#pragma unroll
    for (int k = 0; k < HD; ++k) acc += xs[k] * W[k * HD + t];
    h[row * HD + t] = acc;

    float vs = acc * av_s[t];
    float vd = acc * av_d[t];
#pragma unroll
    for (int off = 32; off > 0; off >>= 1) {
        vs += __shfl_down(vs, off);
        vd += __shfl_down(vd, off);
    }
    __shared__ float red[4];
    if ((t & 63) == 0) { red[t >> 6] = vs; red[2 + (t >> 6)] = vd; }
    __syncthreads();
    if (t == 0) { alp_s[row] = red[0] + red[1]; alp_d[row] = red[2] + red[3]; }
}

// ---------- CSR build ----------
__global__ void k_hist(const int* __restrict__ ei, int E, int Etot, int* __restrict__ deg) {
    int i = blockIdx.x * blockDim.x + threadIdx.x;
    if (i >= Etot) return;
    int d = (i < E) ? ei[E + i] : (i - E);
    atomicAdd(&deg[d], 1);
}

#define SCAN_T 256
__global__ void k_scan(const int* __restrict__ deg, int* __restrict__ ptr,
                       int* __restrict__ cursor, int n) {
    __shared__ int part[SCAN_T];
    int t = threadIdx.x;
    int chunk = (n + SCAN_T - 1) / SCAN_T;
    int lo = t * chunk;
    int hi = lo + chunk; if (hi > n) hi = n;
    int s = 0;
    for (int i = lo; i < hi; ++i) s += deg[i];
    part[t] = s;
    __syncthreads();
    // Hillis-Steele inclusive scan in LDS
    for (int off = 1; off < SCAN_T; off <<= 1) {
        int v = (t >= off) ? part[t - off] : 0;
        __syncthreads();
        part[t] += v;
        __syncthreads();
    }
    int base = (t == 0) ? 0 : part[t - 1];
    for (int i = lo; i < hi; ++i) {
        int dv = deg[i];
        ptr[i] = base;
        cursor[i] = base;
        base += dv;
    }
    if (t == SCAN_T - 1) ptr[n] = base;
}

__global__ void k_fill(const int* __restrict__ ei, int E, int Etot,
                       int* __restrict__ cursor, int* __restrict__ col) {
    int i = blockIdx.x * blockDim.x + threadIdx.x;
    if (i >= Etot) return;
    int s, d;
    if (i < E) { s = ei[i]; d = ei[E + i]; } else { s = d = i - E; }
    col[atomicAdd(&cursor[d], 1)] = s;
}

// ---------- fused GAT aggregation: softmax over in-edges + gather + bias + relu ----------
// one 64-lane wave per destination node; lanes = 2 channels each (HD=128)
__global__ void k_gat_gather(const int* __restrict__ ptr, const int* __restrict__ col,
                             const float* __restrict__ h,
                             const float* __restrict__ alp_s, const float* __restrict__ alp_d,
                             const float* __restrict__ bias, float* __restrict__ out, int n) {
    int node = blockIdx.x * 4 + (threadIdx.x >> 6);
    if (node >= n) return;
    int lane = threadIdx.x & 63;
    int beg = ptr[node], end = ptr[node + 1];
    float ad = alp_d[node];

    // pass 1: segment max (lane-strided over edges, wave reduce)
    float m = -3.4e38f;
    for (int j = beg + lane; j < end; j += 64) {
        float e = alp_s[col[j]] + ad;
        e = e > 0.f ? e : NEG_SLOPE * e;
        m = fmaxf(m, e);
    }
#pragma unroll
    for (int off = 32; off > 0; off >>= 1) m = fmaxf(m, __shfl_xor(m, off));

    // pass 2: weighted aggregation (serial over edges, lanes = channels)
    float acc0 = 0.f, acc1 = 0.f, den = 0.f;
    for (int j = beg; j < end; ++j) {
        int s = col[j];
        float e = alp_s[s] + ad;
        e = e > 0.f ? e : NEG_SLOPE * e;
        float ee = __expf(e - m);
        den += ee;
        acc0 = fmaf(ee, h[s * HD + lane], acc0);
        acc1 = fmaf(ee, h[s * HD + 64 + lane], acc1);
    }
    float inv = 1.f / den;
    float v0 = acc0 * inv + bias[lane];
    float v1 = acc1 * inv + bias[64 + lane];
    out[node * HD + lane]      = v0 > 0.f ? v0 : 0.f;
    out[node * HD + 64 + lane] = v1 > 0.f ? v1 : 0.f;
}

// ---------- pooling ----------
__global__ void k_count(const int* __restrict__ batch, float* __restrict__ counts, int n) {
    int i = blockIdx.x * blockDim.x + threadIdx.x;
    if (i < n) atomicAdd(&counts[batch[i]], 1.0f);
}
__global__ void k_pool(const float* __restrict__ x, const int* __restrict__ batch,
                       float* __restrict__ pooled, int n) {
    int i = blockIdx.x;
    if (i >= n) return;
    int t = threadIdx.x;
    atomicAdd(&pooled[batch[i] * HD + t], x[i * HD + t]);
}

// ---------- doc embedding: relu(doc @ W_doc + b_doc) ----------
__global__ void k_doc(const float* __restrict__ doc, const float* __restrict__ Wd,
                      const float* __restrict__ bd, float* __restrict__ emb) {
    int g = blockIdx.x;
    int t = threadIdx.x;           // 0..127
    __shared__ float ds[DDOC];
    for (int k = t; k < DDOC; k += HD) ds[k] = doc[g * DDOC + k];
    __syncthreads();
    float acc = bd[t];
    for (int k = 0; k < DDOC; ++k) acc += ds[k] * Wd[k * HD + t];
    emb[g * HD + t] = acc > 0.f ? acc : 0.f;
}

// ---------- heads ----------
__global__ void k_head(const float* __restrict__ pooled, const float* __restrict__ counts,
                       const float* __restrict__ emb,
                       const float* __restrict__ Wt, const float* __restrict__ bt,
                       const float* __restrict__ Wm, const float* __restrict__ bm,
                       float* __restrict__ out_task, float* __restrict__ out_time) {
    int g = blockIdx.x;
    int t = threadIdx.x;           // 0..63
    __shared__ float z[2 * HD];
    float cnt = counts[g];
    cnt = cnt < 1.f ? 1.f : cnt;
    for (int k = t; k < HD; k += 64) {
        z[k] = pooled[g * HD + k] / cnt;
        z[HD + k] = emb[g * HD + k];
    }
    __syncthreads();
    if (t < TOUT) {
        float acc = bt[t];
        for (int k = 0; k < 2 * HD; ++k) acc += z[k] * Wt[k * TOUT + t];
        out_task[g * TOUT + t] = acc;
    } else if (t == TOUT) {
        float acc = bm[0];
        for (int k = 0; k < 2 * HD; ++k) acc += z[k] * Wm[k];
        out_time[g] = acc;
    }
}

extern "C" void kernel_launch(void* const* d_in, const int* in_sizes, int n_in,
                              void* d_out, int out_size, void* d_ws, size_t ws_size,
                              hipStream_t stream) {
    const float* x0    = (const float*)d_in[0];
    const int*   ei    = (const int*)d_in[1];
    const int*   batch = (const int*)d_in[2];
    const float* doc   = (const float*)d_in[3];
    const float* W[3]   = {(const float*)d_in[4],  (const float*)d_in[8],  (const float*)d_in[12]};
    const float* a_s[3] = {(const float*)d_in[5],  (const float*)d_in[9],  (const float*)d_in[13]};
    const float* a_d[3] = {(const float*)d_in[6],  (const float*)d_in[10], (const float*)d_in[14]};
    const float* b[3]   = {(const float*)d_in[7],  (const float*)d_in[11], (const float*)d_in[15]};
    const float* Wdoc  = (const float*)d_in[16];
    const float* bdoc  = (const float*)d_in[17];
    const float* Wtask = (const float*)d_in[18];
    const float* btask = (const float*)d_in[19];
    const float* Wtime = (const float*)d_in[20];
    const float* btime = (const float*)d_in[21];

    const int N    = in_sizes[2];
    const int E    = in_sizes[1] / 2;
    const int Etot = E + N;
    const int G    = in_sizes[3] / DDOC;

    // workspace layout
    float* ws = (float*)d_ws;
    float* A      = ws; ws += (size_t)N * HD;   // layer output / next input
    float* Hb     = ws; ws += (size_t)N * HD;   // h = x @ W
    float* alp_s  = ws; ws += N;
    float* alp_d  = ws; ws += N;
    float* pooled = ws; ws += (size_t)G * HD;
    float* counts = ws; ws += G;
    float* emb    = ws; ws += (size_t)G * HD;
    int* deg    = (int*)ws; ws += N;
    int* cursor = (int*)ws; ws += N;
    int* ptr    = (int*)ws; ws += N + 1;
    int* col    = (int*)ws; ws += Etot;

    float* out_task = (float*)d_out;
    float* out_time = out_task + (size_t)G * TOUT;

    const int thr = 256;
    const int nBlocks = (N + thr - 1) / thr;
    const int eBlocks = (Etot + thr - 1) / thr;

    // ---- build CSR (dst-sorted adjacency), reused by all 3 layers ----
    k_zero_int<<<nBlocks, thr, 0, stream>>>(deg, N);
    k_hist<<<eBlocks, thr, 0, stream>>>(ei, E, Etot, deg);
    k_scan<<<1, SCAN_T, 0, stream>>>(deg, ptr, cursor, N);
    k_fill<<<eBlocks, thr, 0, stream>>>(ei, E, Etot, cursor, col);

    // ---- 3 GAT layers ----
    const float* xin = x0;
    for (int l = 0; l < 3; ++l) {
        k_gemm_alpha<<<N, HD, 0, stream>>>(xin, W[l], a_s[l], a_d[l], Hb, alp_s, alp_d, N);
        k_gat_gather<<<(N + 3) / 4, thr, 0, stream>>>(ptr, col, Hb, alp_s, alp_d, b[l], A, N);
        xin = A;
    }

    // ---- global mean pool ----
    k_zero<<<(G * HD + thr - 1) / thr, thr, 0, stream>>>(pooled, G * HD);
    k_zero<<<1, thr, 0, stream>>>(counts, G);
    k_count<<<nBlocks, thr, 0, stream>>>(batch, counts, N);
    k_pool<<<N, HD, 0, stream>>>(A, batch, pooled, N);

    // ---- doc embedding + heads ----
    k_doc<<<G, HD, 0, stream>>>(doc, Wdoc, bdoc, emb);
    k_head<<<G, 64, 0, stream>>>(pooled, counts, emb, Wtask, btask, Wtime, btime,
                                 out_task, out_time);
}

// Round 3
// 548.846 us; speedup vs baseline: 2.6318x; 1.2913x over previous
//
#include <hip/hip_runtime.h>

#define HD 128          // hidden dim (== DIN)
#define DDOC 512
#define TOUT 32
#define RB 16           // rows per block in gemm
constexpr float NEG_SLOPE = 0.2f;

// ---------- zero ----------
__global__ void k_zero_int(int* __restrict__ p, int n) {
    int i = blockIdx.x * blockDim.x + threadIdx.x;
    if (i < n) p[i] = 0;
}

// ---------- tiled GEMM + fused alpha: h = x@W, alpha = h.a ----------
// 256 threads, 16 rows/block; thread owns col c = t&127, rows rg*8..rg*8+7
__global__ void k_gemm_alpha(const float* __restrict__ x, const float* __restrict__ W,
                             const float* __restrict__ av_s, const float* __restrict__ av_d,
                             float* __restrict__ h, float* __restrict__ alp_s,
                             float* __restrict__ alp_d, int n) {
    int row0 = blockIdx.x * RB;
    int t = threadIdx.x;            // 0..255
    int c = t & (HD - 1);
    int rg = t >> 7;                // 0: rows 0-7, 1: rows 8-15

    __shared__ float xs[RB][HD];
    for (int i = t; i < RB * HD; i += 256) {
        int r = i >> 7, k = i & (HD - 1);
        int row = row0 + r;
        xs[r][k] = (row < n) ? x[row * HD + k] : 0.f;
    }
    __syncthreads();

    float acc[8] = {0.f, 0.f, 0.f, 0.f, 0.f, 0.f, 0.f, 0.f};
    for (int k = 0; k < HD; ++k) {
        float w = W[k * HD + c];
#pragma unroll
        for (int r = 0; r < 8; ++r) acc[r] = fmaf(xs[rg * 8 + r][k], w, acc[r]);
    }
#pragma unroll
    for (int r = 0; r < 8; ++r) {
        int row = row0 + rg * 8 + r;
        if (row < n) h[row * HD + c] = acc[r];
    }

    // fused alpha_src/dst = h . a  (wave shuffle + cross-wave LDS combine)
    float as = av_s[c], ad = av_d[c];
    __shared__ float redS[4][8], redD[4][8];
    int wave = t >> 6, lane = t & 63;
#pragma unroll
    for (int r = 0; r < 8; ++r) {
        float vs = acc[r] * as;
        float vd = acc[r] * ad;
#pragma unroll
        for (int off = 32; off > 0; off >>= 1) {
            vs += __shfl_xor(vs, off);
            vd += __shfl_xor(vd, off);
        }
        if (lane == 0) { redS[wave][r] = vs; redD[wave][r] = vd; }
    }
    __syncthreads();
    if (t < RB) {
        int w0 = (t < 8) ? 0 : 2;
        int rr = t & 7;
        int row = row0 + t;
        if (row < n) {
            alp_s[row] = redS[w0][rr] + redS[w0 + 1][rr];
            alp_d[row] = redD[w0][rr] + redD[w0 + 1][rr];
        }
    }
}

// ---------- CSR build ----------
__global__ void k_hist(const int* __restrict__ ei, int E, int Etot, int* __restrict__ deg) {
    int i = blockIdx.x * blockDim.x + threadIdx.x;
    if (i >= Etot) return;
    int d = (i < E) ? ei[E + i] : (i - E);
    atomicAdd(&deg[d], 1);
}

#define SCAN_T 256
__global__ void k_scan(const int* __restrict__ deg, int* __restrict__ ptr,
                       int* __restrict__ cursor, int n) {
    __shared__ int part[SCAN_T];
    int t = threadIdx.x;
    int chunk = (n + SCAN_T - 1) / SCAN_T;
    int lo = t * chunk;
    int hi = lo + chunk; if (hi > n) hi = n;
    int s = 0;
    for (int i = lo; i < hi; ++i) s += deg[i];
    part[t] = s;
    __syncthreads();
    for (int off = 1; off < SCAN_T; off <<= 1) {
        int v = (t >= off) ? part[t - off] : 0;
        __syncthreads();
        part[t] += v;
        __syncthreads();
    }
    int base = (t == 0) ? 0 : part[t - 1];
    for (int i = lo; i < hi; ++i) {
        int dv = deg[i];
        ptr[i] = base;
        cursor[i] = base;
        base += dv;
    }
    if (t == SCAN_T - 1) ptr[n] = base;
}

__global__ void k_fill(const int* __restrict__ ei, int E, int Etot,
                       int* __restrict__ cursor, int* __restrict__ col) {
    int i = blockIdx.x * blockDim.x + threadIdx.x;
    if (i >= Etot) return;
    int s, d;
    if (i < E) { s = ei[i]; d = ei[E + i]; } else { s = d = i - E; }
    col[atomicAdd(&cursor[d], 1)] = s;
}

// ---------- fused GAT aggregation: softmax over in-edges + gather + bias + relu ----------
__global__ void k_gat_gather(const int* __restrict__ ptr, const int* __restrict__ col,
                             const float* __restrict__ h,
                             const float* __restrict__ alp_s, const float* __restrict__ alp_d,
                             const float* __restrict__ bias, float* __restrict__ out, int n) {
    int node = blockIdx.x * 4 + (threadIdx.x >> 6);
    if (node >= n) return;
    int lane = threadIdx.x & 63;
    int beg = ptr[node], end = ptr[node + 1];
    float ad = alp_d[node];

    float m = -3.4e38f;
    for (int j = beg + lane; j < end; j += 64) {
        float e = alp_s[col[j]] + ad;
        e = e > 0.f ? e : NEG_SLOPE * e;
        m = fmaxf(m, e);
    }
#pragma unroll
    for (int off = 32; off > 0; off >>= 1) m = fmaxf(m, __shfl_xor(m, off));

    float acc0 = 0.f, acc1 = 0.f, den = 0.f;
    for (int j = beg; j < end; ++j) {
        int s = col[j];
        float e = alp_s[s] + ad;
        e = e > 0.f ? e : NEG_SLOPE * e;
        float ee = __expf(e - m);
        den += ee;
        acc0 = fmaf(ee, h[s * HD + lane], acc0);
        acc1 = fmaf(ee, h[s * HD + 64 + lane], acc1);
    }
    float inv = 1.f / den;
    float v0 = acc0 * inv + bias[lane];
    float v1 = acc1 * inv + bias[64 + lane];
    out[node * HD + lane]      = v0 > 0.f ? v0 : 0.f;
    out[node * HD + 64 + lane] = v1 > 0.f ? v1 : 0.f;
}

// ---------- graph boundaries via binary search on sorted batch ----------
__global__ void k_gptr(const int* __restrict__ batch, int* __restrict__ gptr, int n, int G) {
    int g = threadIdx.x;
    if (g > G) return;
    if (g == G) { gptr[G] = n; return; }
    int lo = 0, hi = n;
    while (lo < hi) {
        int mid = (lo + hi) >> 1;
        if (batch[mid] < g) lo = mid + 1; else hi = mid;
    }
    gptr[g] = lo;
}

// ---------- mean pool over contiguous row range (no atomics) ----------
__global__ void k_pool_seq(const float* __restrict__ x, const int* __restrict__ gptr,
                           float* __restrict__ pooled) {
    int g = blockIdx.x;
    int t = threadIdx.x;            // 0..255
    int ch = t & (HD - 1);
    int half = t >> 7;
    int beg = gptr[g], end = gptr[g + 1];
    float acc = 0.f;
    for (int r = beg + half; r < end; r += 2) acc += x[r * HD + ch];
    __shared__ float red[2][HD];
    red[half][ch] = acc;
    __syncthreads();
    if (t < HD) {
        float cnt = (float)(end - beg);
        cnt = cnt < 1.f ? 1.f : cnt;
        pooled[g * HD + t] = (red[0][t] + red[1][t]) / cnt;
    }
}

// ---------- doc embedding: relu(doc @ W_doc + b_doc) ----------
__global__ void k_doc(const float* __restrict__ doc, const float* __restrict__ Wd,
                      const float* __restrict__ bd, float* __restrict__ emb) {
    int g = blockIdx.x;
    int t = threadIdx.x;            // 0..127
    __shared__ float ds[DDOC];
    for (int k = t; k < DDOC; k += HD) ds[k] = doc[g * DDOC + k];
    __syncthreads();
    float acc = bd[t];
    for (int k = 0; k < DDOC; ++k) acc += ds[k] * Wd[k * HD + t];
    emb[g * HD + t] = acc > 0.f ? acc : 0.f;
}

// ---------- heads (pooled already holds the mean) ----------
__global__ void k_head(const float* __restrict__ pooled, const float* __restrict__ emb,
                       const float* __restrict__ Wt, const float* __restrict__ bt,
                       const float* __restrict__ Wm, const float* __restrict__ bm,
                       float* __restrict__ out_task, float* __restrict__ out_time) {
    int g = blockIdx.x;
    int t = threadIdx.x;            // 0..63
    __shared__ float z[2 * HD];
    for (int k = t; k < HD; k += 64) {
        z[k] = pooled[g * HD + k];
        z[HD + k] = emb[g * HD + k];
    }
    __syncthreads();
    if (t < TOUT) {
        float acc = bt[t];
        for (int k = 0; k < 2 * HD; ++k) acc += z[k] * Wt[k * TOUT + t];
        out_task[g * TOUT + t] = acc;
    } else if (t == TOUT) {
        float acc = bm[0];
        for (int k = 0; k < 2 * HD; ++k) acc += z[k] * Wm[k];
        out_time[g] = acc;
    }
}

extern "C" void kernel_launch(void* const* d_in, const int* in_sizes, int n_in,
                              void* d_out, int out_size, void* d_ws, size_t ws_size,
                              hipStream_t stream) {
    const float* x0    = (const float*)d_in[0];
    const int*   ei    = (const int*)d_in[1];
    const int*   batch = (const int*)d_in[2];
    const float* doc   = (const float*)d_in[3];
    const float* W[3]   = {(const float*)d_in[4],  (const float*)d_in[8],  (const float*)d_in[12]};
    const float* a_s[3] = {(const float*)d_in[5],  (const float*)d_in[9],  (const float*)d_in[13]};
    const float* a_d[3] = {(const float*)d_in[6],  (const float*)d_in[10], (const float*)d_in[14]};
    const float* b[3]   = {(const float*)d_in[7],  (const float*)d_in[11], (const float*)d_in[15]};
    const float* Wdoc  = (const float*)d_in[16];
    const float* bdoc  = (const float*)d_in[17];
    const float* Wtask = (const float*)d_in[18];
    const float* btask = (const float*)d_in[19];
    const float* Wtime = (const float*)d_in[20];
    const float* btime = (const float*)d_in[21];

    const int N    = in_sizes[2];
    const int E    = in_sizes[1] / 2;
    const int Etot = E + N;
    const int G    = in_sizes[3] / DDOC;

    // workspace layout
    float* ws = (float*)d_ws;
    float* A      = ws; ws += (size_t)N * HD;   // layer output / next input
    float* Hb     = ws; ws += (size_t)N * HD;   // h = x @ W
    float* alp_s  = ws; ws += N;
    float* alp_d  = ws; ws += N;
    float* pooled = ws; ws += (size_t)G * HD;
    float* emb    = ws; ws += (size_t)G * HD;
    int* deg    = (int*)ws; ws += N;
    int* cursor = (int*)ws; ws += N;
    int* ptr    = (int*)ws; ws += N + 1;
    int* gptr   = (int*)ws; ws += G + 1;
    int* col    = (int*)ws; ws += Etot;

    float* out_task = (float*)d_out;
    float* out_time = out_task + (size_t)G * TOUT;

    const int thr = 256;
    const int nBlocks = (N + thr - 1) / thr;
    const int eBlocks = (Etot + thr - 1) / thr;

    // ---- build CSR (dst-sorted adjacency), reused by all 3 layers ----
    k_zero_int<<<nBlocks, thr, 0, stream>>>(deg, N);
    k_hist<<<eBlocks, thr, 0, stream>>>(ei, E, Etot, deg);
    k_scan<<<1, SCAN_T, 0, stream>>>(deg, ptr, cursor, N);
    k_fill<<<eBlocks, thr, 0, stream>>>(ei, E, Etot, cursor, col);

    // ---- graph boundaries ----
    k_gptr<<<1, G + 1, 0, stream>>>(batch, gptr, N, G);

    // ---- 3 GAT layers ----
    const float* xin = x0;
    for (int l = 0; l < 3; ++l) {
        k_gemm_alpha<<<(N + RB - 1) / RB, thr, 0, stream>>>(xin, W[l], a_s[l], a_d[l],
                                                            Hb, alp_s, alp_d, N);
        k_gat_gather<<<(N + 3) / 4, thr, 0, stream>>>(ptr, col, Hb, alp_s, alp_d, b[l], A, N);
        xin = A;
    }

    // ---- global mean pool (contiguous segments, no atomics) ----
    k_pool_seq<<<G, thr, 0, stream>>>(A, gptr, pooled);

    // ---- doc embedding + heads ----
    k_doc<<<G, HD, 0, stream>>>(doc, Wdoc, bdoc, emb);
    k_head<<<G, 64, 0, stream>>>(pooled, emb, Wtask, btask, Wtime, btime,
                                 out_task, out_time);
}

// Round 4
// 469.787 us; speedup vs baseline: 3.0747x; 1.1683x over previous
//
#include <hip/hip_runtime.h>

#define HD 128          // hidden dim (== DIN)
#define DDOC 512
#define TOUT 32
#define RB 16           // rows per block in gemm
constexpr float NEG_SLOPE = 0.2f;

// ---------- zero ----------
__global__ void k_zero_int(int* __restrict__ p, int n) {
    int i = blockIdx.x * blockDim.x + threadIdx.x;
    if (i < n) p[i] = 0;
}

// ---------- tiled GEMM + fused alpha: h = x@W, alpha = h.a ----------
__global__ void k_gemm_alpha(const float* __restrict__ x, const float* __restrict__ W,
                             const float* __restrict__ av_s, const float* __restrict__ av_d,
                             float* __restrict__ h, float* __restrict__ alp_s,
                             float* __restrict__ alp_d, int n) {
    int row0 = blockIdx.x * RB;
    int t = threadIdx.x;            // 0..255
    int c = t & (HD - 1);
    int rg = t >> 7;                // 0: rows 0-7, 1: rows 8-15

    __shared__ float xs[RB][HD];
    for (int i = t; i < RB * HD; i += 256) {
        int r = i >> 7, k = i & (HD - 1);
        int row = row0 + r;
        xs[r][k] = (row < n) ? x[row * HD + k] : 0.f;
    }
    __syncthreads();

    float acc[8] = {0.f, 0.f, 0.f, 0.f, 0.f, 0.f, 0.f, 0.f};
    for (int k = 0; k < HD; ++k) {
        float w = W[k * HD + c];
#pragma unroll
        for (int r = 0; r < 8; ++r) acc[r] = fmaf(xs[rg * 8 + r][k], w, acc[r]);
    }
#pragma unroll
    for (int r = 0; r < 8; ++r) {
        int row = row0 + rg * 8 + r;
        if (row < n) h[row * HD + c] = acc[r];
    }

    float as = av_s[c], ad = av_d[c];
    __shared__ float redS[4][8], redD[4][8];
    int wave = t >> 6, lane = t & 63;
#pragma unroll
    for (int r = 0; r < 8; ++r) {
        float vs = acc[r] * as;
        float vd = acc[r] * ad;
#pragma unroll
        for (int off = 32; off > 0; off >>= 1) {
            vs += __shfl_xor(vs, off);
            vd += __shfl_xor(vd, off);
        }
        if (lane == 0) { redS[wave][r] = vs; redD[wave][r] = vd; }
    }
    __syncthreads();
    if (t < RB) {
        int w0 = (t < 8) ? 0 : 2;
        int rr = t & 7;
        int row = row0 + t;
        if (row < n) {
            alp_s[row] = redS[w0][rr] + redS[w0 + 1][rr];
            alp_d[row] = redD[w0][rr] + redD[w0 + 1][rr];
        }
    }
}

// ---------- CSR build ----------
__global__ void k_hist(const int* __restrict__ ei, int E, int Etot, int* __restrict__ deg) {
    int i = blockIdx.x * blockDim.x + threadIdx.x;
    if (i >= Etot) return;
    int d = (i < E) ? ei[E + i] : (i - E);
    atomicAdd(&deg[d], 1);
}

#define SCAN_T 256
__global__ void k_scan(const int* __restrict__ deg, int* __restrict__ ptr,
                       int* __restrict__ cursor, int n) {
    __shared__ int part[SCAN_T];
    int t = threadIdx.x;
    int chunk = (n + SCAN_T - 1) / SCAN_T;
    int lo = t * chunk;
    int hi = lo + chunk; if (hi > n) hi = n;
    int s = 0;
    for (int i = lo; i < hi; ++i) s += deg[i];
    part[t] = s;
    __syncthreads();
    for (int off = 1; off < SCAN_T; off <<= 1) {
        int v = (t >= off) ? part[t - off] : 0;
        __syncthreads();
        part[t] += v;
        __syncthreads();
    }
    int base = (t == 0) ? 0 : part[t - 1];
    for (int i = lo; i < hi; ++i) {
        int dv = deg[i];
        ptr[i] = base;
        cursor[i] = base;
        base += dv;
    }
    if (t == SCAN_T - 1) ptr[n] = base;
}

__global__ void k_fill(const int* __restrict__ ei, int E, int Etot,
                       int* __restrict__ cursor, int* __restrict__ col) {
    int i = blockIdx.x * blockDim.x + threadIdx.x;
    if (i >= Etot) return;
    int s, d;
    if (i < E) { s = ei[i]; d = ei[E + i]; } else { s = d = i - E; }
    col[atomicAdd(&cursor[d], 1)] = s;
}

// ---------- fused GAT aggregation ----------
// one 64-lane wave per dst node. Phase A: edge metadata (col, softmax weight)
// lane-strided into REGISTERS (deg<=64 ~always; global wbuf fallback).
// Phase B: 2 edges/iter, half-wave each, float4 row loads; weights via shuffle.
__global__ void k_gat_gather(const int* __restrict__ ptr, const int* __restrict__ col,
                             const float* __restrict__ h,
                             const float* __restrict__ alp_s, const float* __restrict__ alp_d,
                             const float* __restrict__ bias, float* __restrict__ wbuf,
                             float* __restrict__ out, int n) {
    int node = blockIdx.x * 4 + (threadIdx.x >> 6);
    if (node >= n) return;
    int lane = threadIdx.x & 63;
    int beg = ptr[node], end = ptr[node + 1];
    int deg = end - beg;
    float ad = alp_d[node];

    // ---- phase A: e, wave-max, exp, denom ----
    float m = -3.4e38f;
    float e_reg = 0.f;
    int   c_reg = 0;
    if (deg <= 64) {
        if (lane < deg) {
            int s = col[beg + lane];
            c_reg = s;
            float e = alp_s[s] + ad;
            e = e > 0.f ? e : NEG_SLOPE * e;
            e_reg = e;
            m = e;
        }
    } else {
        for (int j = beg + lane; j < end; j += 64) {
            int s = col[j];
            float e = alp_s[s] + ad;
            e = e > 0.f ? e : NEG_SLOPE * e;
            wbuf[j] = e;
            m = fmaxf(m, e);
        }
    }
#pragma unroll
    for (int off = 32; off > 0; off >>= 1) m = fmaxf(m, __shfl_xor(m, off));

    float den = 0.f;
    if (deg <= 64) {
        float ee = (lane < deg) ? __expf(e_reg - m) : 0.f;
        e_reg = ee;
        den = ee;
    } else {
        for (int j = beg + lane; j < end; j += 64) {
            float ee = __expf(wbuf[j] - m);
            wbuf[j] = ee;
            den += ee;
        }
    }
#pragma unroll
    for (int off = 32; off > 0; off >>= 1) den += __shfl_xor(den, off);

    // ---- phase B: weighted aggregation ----
    const float4* __restrict__ h4 = (const float4*)h;
    int half = lane >> 5;
    int l32 = lane & 31;
    float4 acc = make_float4(0.f, 0.f, 0.f, 0.f);
    if (deg <= 64) {
#pragma unroll 2
        for (int j = beg; j < end; j += 2) {
            int idx = j + half;
            int t = (idx < end) ? (idx - beg) : (deg - 1);
            int s = __shfl(c_reg, t);
            float w = __shfl(e_reg, t);
            if (idx >= end) w = 0.f;
            float4 hv = h4[(size_t)s * 32 + l32];
            acc.x = fmaf(w, hv.x, acc.x);
            acc.y = fmaf(w, hv.y, acc.y);
            acc.z = fmaf(w, hv.z, acc.z);
            acc.w = fmaf(w, hv.w, acc.w);
        }
    } else {
#pragma unroll 2
        for (int j = beg; j < end; j += 2) {
            int idx = j + half;
            int ii = (idx < end) ? idx : (end - 1);
            int s = col[ii];
            float w = (idx < end) ? wbuf[ii] : 0.f;
            float4 hv = h4[(size_t)s * 32 + l32];
            acc.x = fmaf(w, hv.x, acc.x);
            acc.y = fmaf(w, hv.y, acc.y);
            acc.z = fmaf(w, hv.z, acc.z);
            acc.w = fmaf(w, hv.w, acc.w);
        }
    }
    // combine the two half-wave partial sums
    acc.x += __shfl_xor(acc.x, 32);
    acc.y += __shfl_xor(acc.y, 32);
    acc.z += __shfl_xor(acc.z, 32);
    acc.w += __shfl_xor(acc.w, 32);

    if (half == 0) {
        float inv = 1.f / den;
        float4 bb = ((const float4*)bias)[l32];
        float4 o;
        o.x = fmaf(acc.x, inv, bb.x); o.x = o.x > 0.f ? o.x : 0.f;
        o.y = fmaf(acc.y, inv, bb.y); o.y = o.y > 0.f ? o.y : 0.f;
        o.z = fmaf(acc.z, inv, bb.z); o.z = o.z > 0.f ? o.z : 0.f;
        o.w = fmaf(acc.w, inv, bb.w); o.w = o.w > 0.f ? o.w : 0.f;
        ((float4*)out)[(size_t)node * 32 + l32] = o;
    }
}

// ---------- graph boundaries via binary search on sorted batch ----------
__global__ void k_gptr(const int* __restrict__ batch, int* __restrict__ gptr, int n, int G) {
    int g = threadIdx.x;
    if (g > G) return;
    if (g == G) { gptr[G] = n; return; }
    int lo = 0, hi = n;
    while (lo < hi) {
        int mid = (lo + hi) >> 1;
        if (batch[mid] < g) lo = mid + 1; else hi = mid;
    }
    gptr[g] = lo;
}

// ---------- mean pool over contiguous row range (no atomics) ----------
__global__ void k_pool_seq(const float* __restrict__ x, const int* __restrict__ gptr,
                           float* __restrict__ pooled) {
    int g = blockIdx.x;
    int t = threadIdx.x;            // 0..255
    int ch = t & (HD - 1);
    int half = t >> 7;
    int beg = gptr[g], end = gptr[g + 1];
    float acc = 0.f;
    for (int r = beg + half; r < end; r += 2) acc += x[r * HD + ch];
    __shared__ float red[2][HD];
    red[half][ch] = acc;
    __syncthreads();
    if (t < HD) {
        float cnt = (float)(end - beg);
        cnt = cnt < 1.f ? 1.f : cnt;
        pooled[g * HD + t] = (red[0][t] + red[1][t]) / cnt;
    }
}

// ---------- doc embedding: relu(doc @ W_doc + b_doc) ----------
__global__ void k_doc(const float* __restrict__ doc, const float* __restrict__ Wd,
                      const float* __restrict__ bd, float* __restrict__ emb) {
    int g = blockIdx.x;
    int t = threadIdx.x;            // 0..127
    __shared__ float ds[DDOC];
    for (int k = t; k < DDOC; k += HD) ds[k] = doc[g * DDOC + k];
    __syncthreads();
    float acc = bd[t];
    for (int k = 0; k < DDOC; ++k) acc += ds[k] * Wd[k * HD + t];
    emb[g * HD + t] = acc > 0.f ? acc : 0.f;
}

// ---------- heads ----------
__global__ void k_head(const float* __restrict__ pooled, const float* __restrict__ emb,
                       const float* __restrict__ Wt, const float* __restrict__ bt,
                       const float* __restrict__ Wm, const float* __restrict__ bm,
                       float* __restrict__ out_task, float* __restrict__ out_time) {
    int g = blockIdx.x;
    int t = threadIdx.x;            // 0..63
    __shared__ float z[2 * HD];
    for (int k = t; k < HD; k += 64) {
        z[k] = pooled[g * HD + k];
        z[HD + k] = emb[g * HD + k];
    }
    __syncthreads();
    if (t < TOUT) {
        float acc = bt[t];
        for (int k = 0; k < 2 * HD; ++k) acc += z[k] * Wt[k * TOUT + t];
        out_task[g * TOUT + t] = acc;
    } else if (t == TOUT) {
        float acc = bm[0];
        for (int k = 0; k < 2 * HD; ++k) acc += z[k] * Wm[k];
        out_time[g] = acc;
    }
}

extern "C" void kernel_launch(void* const* d_in, const int* in_sizes, int n_in,
                              void* d_out, int out_size, void* d_ws, size_t ws_size,
                              hipStream_t stream) {
    const float* x0    = (const float*)d_in[0];
    const int*   ei    = (const int*)d_in[1];
    const int*   batch = (const int*)d_in[2];
    const float* doc   = (const float*)d_in[3];
    const float* W[3]   = {(const float*)d_in[4],  (const float*)d_in[8],  (const float*)d_in[12]};
    const float* a_s[3] = {(const float*)d_in[5],  (const float*)d_in[9],  (const float*)d_in[13]};
    const float* a_d[3] = {(const float*)d_in[6],  (const float*)d_in[10], (const float*)d_in[14]};
    const float* b[3]   = {(const float*)d_in[7],  (const float*)d_in[11], (const float*)d_in[15]};
    const float* Wdoc  = (const float*)d_in[16];
    const float* bdoc  = (const float*)d_in[17];
    const float* Wtask = (const float*)d_in[18];
    const float* btask = (const float*)d_in[19];
    const float* Wtime = (const float*)d_in[20];
    const float* btime = (const float*)d_in[21];

    const int N    = in_sizes[2];
    const int E    = in_sizes[1] / 2;
    const int Etot = E + N;
    const int G    = in_sizes[3] / DDOC;

    // workspace layout
    float* ws = (float*)d_ws;
    float* A      = ws; ws += (size_t)N * HD;   // layer output / next input
    float* Hb     = ws; ws += (size_t)N * HD;   // h = x @ W
    float* alp_s  = ws; ws += N;
    float* alp_d  = ws; ws += N;
    float* wbuf   = ws; ws += Etot;             // fallback softmax weights (deg>64)
    float* pooled = ws; ws += (size_t)G * HD;
    float* emb    = ws; ws += (size_t)G * HD;
    int* deg    = (int*)ws; ws += N;
    int* cursor = (int*)ws; ws += N;
    int* ptr    = (int*)ws; ws += N + 1;
    int* gptr   = (int*)ws; ws += G + 1;
    int* col    = (int*)ws; ws += Etot;

    float* out_task = (float*)d_out;
    float* out_time = out_task + (size_t)G * TOUT;

    const int thr = 256;
    const int nBlocks = (N + thr - 1) / thr;
    const int eBlocks = (Etot + thr - 1) / thr;

    // ---- build CSR (dst-sorted adjacency), reused by all 3 layers ----
    k_zero_int<<<nBlocks, thr, 0, stream>>>(deg, N);
    k_hist<<<eBlocks, thr, 0, stream>>>(ei, E, Etot, deg);
    k_scan<<<1, SCAN_T, 0, stream>>>(deg, ptr, cursor, N);
    k_fill<<<eBlocks, thr, 0, stream>>>(ei, E, Etot, cursor, col);

    // ---- graph boundaries ----
    k_gptr<<<1, G + 1, 0, stream>>>(batch, gptr, N, G);

    // ---- 3 GAT layers ----
    const float* xin = x0;
    for (int l = 0; l < 3; ++l) {
        k_gemm_alpha<<<(N + RB - 1) / RB, thr, 0, stream>>>(xin, W[l], a_s[l], a_d[l],
                                                            Hb, alp_s, alp_d, N);
        k_gat_gather<<<(N + 3) / 4, thr, 0, stream>>>(ptr, col, Hb, alp_s, alp_d, b[l],
                                                      wbuf, A, N);
        xin = A;
    }

    // ---- global mean pool (contiguous segments, no atomics) ----
    k_pool_seq<<<G, thr, 0, stream>>>(A, gptr, pooled);

    // ---- doc embedding + heads ----
    k_doc<<<G, HD, 0, stream>>>(doc, Wdoc, bdoc, emb);
    k_head<<<G, 64, 0, stream>>>(pooled, emb, Wtask, btask, Wtime, btime,
                                 out_task, out_time);
}

// Round 5
// 410.111 us; speedup vs baseline: 3.5221x; 1.1455x over previous
//
#include <hip/hip_runtime.h>

#define HD 128          // hidden dim (== DIN)
#define DDOC 512
#define TOUT 32
#define RB 16           // rows per block in gemm
#define SCANB 256
constexpr float NEG_SLOPE = 0.2f;

// ---------- zero ----------
__global__ void k_zero_int(int* __restrict__ p, int n) {
    int i = blockIdx.x * blockDim.x + threadIdx.x;
    if (i < n) p[i] = 0;
}

// ---------- tiled GEMM + fused alpha: h = x@W, alpha = h.a ----------
__global__ void k_gemm_alpha(const float* __restrict__ x, const float* __restrict__ W,
                             const float* __restrict__ av_s, const float* __restrict__ av_d,
                             float* __restrict__ h, float* __restrict__ alp_s,
                             float* __restrict__ alp_d, int n) {
    int row0 = blockIdx.x * RB;
    int t = threadIdx.x;            // 0..255
    int c = t & (HD - 1);
    int rg = t >> 7;                // 0: rows 0-7, 1: rows 8-15

    __shared__ float xs[RB][HD];
    for (int i = t; i < RB * HD; i += 256) {
        int r = i >> 7, k = i & (HD - 1);
        int row = row0 + r;
        xs[r][k] = (row < n) ? x[row * HD + k] : 0.f;
    }
    __syncthreads();

    float acc[8] = {0.f, 0.f, 0.f, 0.f, 0.f, 0.f, 0.f, 0.f};
    for (int k = 0; k < HD; ++k) {
        float w = W[k * HD + c];
#pragma unroll
        for (int r = 0; r < 8; ++r) acc[r] = fmaf(xs[rg * 8 + r][k], w, acc[r]);
    }
#pragma unroll
    for (int r = 0; r < 8; ++r) {
        int row = row0 + rg * 8 + r;
        if (row < n) h[row * HD + c] = acc[r];
    }

    float as = av_s[c], ad = av_d[c];
    __shared__ float redS[4][8], redD[4][8];
    int wave = t >> 6, lane = t & 63;
#pragma unroll
    for (int r = 0; r < 8; ++r) {
        float vs = acc[r] * as;
        float vd = acc[r] * ad;
#pragma unroll
        for (int off = 32; off > 0; off >>= 1) {
            vs += __shfl_xor(vs, off);
            vd += __shfl_xor(vd, off);
        }
        if (lane == 0) { redS[wave][r] = vs; redD[wave][r] = vd; }
    }
    __syncthreads();
    if (t < RB) {
        int w0 = (t < 8) ? 0 : 2;
        int rr = t & 7;
        int row = row0 + t;
        if (row < n) {
            alp_s[row] = redS[w0][rr] + redS[w0 + 1][rr];
            alp_d[row] = redD[w0][rr] + redD[w0 + 1][rr];
        }
    }
}

// ---------- CSR build ----------
__global__ void k_hist(const int* __restrict__ ei, int E, int Etot, int* __restrict__ deg) {
    int i = blockIdx.x * blockDim.x + threadIdx.x;
    if (i >= Etot) return;
    int d = (i < E) ? ei[E + i] : (i - E);
    atomicAdd(&deg[d], 1);
}

// ---------- 3-phase device-wide exclusive scan of deg -> ptr/cursor ----------
__global__ void k_scan_part(const int* __restrict__ deg, int* __restrict__ bsum, int n) {
    int t = threadIdx.x;
    int i = blockIdx.x * SCANB + t;
    int v = (i < n) ? deg[i] : 0;
#pragma unroll
    for (int off = 32; off > 0; off >>= 1) v += __shfl_xor(v, off);
    __shared__ int red[4];
    if ((t & 63) == 0) red[t >> 6] = v;
    __syncthreads();
    if (t == 0) bsum[blockIdx.x] = red[0] + red[1] + red[2] + red[3];
}

__global__ void k_scan_bsum(int* __restrict__ bsum, int nb) {
    __shared__ int part[SCANB];
    int t = threadIdx.x;
    int v = (t < nb) ? bsum[t] : 0;
    part[t] = v;
    __syncthreads();
    for (int off = 1; off < SCANB; off <<= 1) {
        int u = (t >= off) ? part[t - off] : 0;
        __syncthreads();
        part[t] += u;
        __syncthreads();
    }
    if (t < nb) bsum[t] = part[t] - v;   // exclusive
}

__global__ void k_scan_final(const int* __restrict__ deg, const int* __restrict__ bsum,
                             int* __restrict__ ptr, int* __restrict__ cursor,
                             int n, int total) {
    __shared__ int part[SCANB];
    int t = threadIdx.x;
    int i = blockIdx.x * SCANB + t;
    int v = (i < n) ? deg[i] : 0;
    part[t] = v;
    __syncthreads();
    for (int off = 1; off < SCANB; off <<= 1) {
        int u = (t >= off) ? part[t - off] : 0;
        __syncthreads();
        part[t] += u;
        __syncthreads();
    }
    if (i < n) {
        int excl = bsum[blockIdx.x] + part[t] - v;
        ptr[i] = excl;
        cursor[i] = excl;
    }
    if (i == n - 1) ptr[n] = total;
}

__global__ void k_fill(const int* __restrict__ ei, int E, int Etot,
                       int* __restrict__ cursor, int* __restrict__ col) {
    int i = blockIdx.x * blockDim.x + threadIdx.x;
    if (i >= Etot) return;
    int s, d;
    if (i < E) { s = ei[i]; d = ei[E + i]; } else { s = d = i - E; }
    col[atomicAdd(&cursor[d], 1)] = s;
}

// ---------- fused GAT aggregation ----------
__global__ void k_gat_gather(const int* __restrict__ ptr, const int* __restrict__ col,
                             const float* __restrict__ h,
                             const float* __restrict__ alp_s, const float* __restrict__ alp_d,
                             const float* __restrict__ bias, float* __restrict__ wbuf,
                             float* __restrict__ out, int n) {
    int node = blockIdx.x * 4 + (threadIdx.x >> 6);
    if (node >= n) return;
    int lane = threadIdx.x & 63;
    int beg = ptr[node], end = ptr[node + 1];
    int deg = end - beg;
    float ad = alp_d[node];

    // ---- phase A: e, wave-max, exp, denom ----
    float m = -3.4e38f;
    float e_reg = 0.f;
    int   c_reg = 0;
    if (deg <= 64) {
        if (lane < deg) {
            int s = col[beg + lane];
            c_reg = s;
            float e = alp_s[s] + ad;
            e = e > 0.f ? e : NEG_SLOPE * e;
            e_reg = e;
            m = e;
        }
    } else {
        for (int j = beg + lane; j < end; j += 64) {
            int s = col[j];
            float e = alp_s[s] + ad;
            e = e > 0.f ? e : NEG_SLOPE * e;
            wbuf[j] = e;
            m = fmaxf(m, e);
        }
    }
#pragma unroll
    for (int off = 32; off > 0; off >>= 1) m = fmaxf(m, __shfl_xor(m, off));

    float den = 0.f;
    if (deg <= 64) {
        float ee = (lane < deg) ? __expf(e_reg - m) : 0.f;
        e_reg = ee;
        den = ee;
    } else {
        for (int j = beg + lane; j < end; j += 64) {
            float ee = __expf(wbuf[j] - m);
            wbuf[j] = ee;
            den += ee;
        }
    }
#pragma unroll
    for (int off = 32; off > 0; off >>= 1) den += __shfl_xor(den, off);

    // ---- phase B: weighted aggregation ----
    const float4* __restrict__ h4 = (const float4*)h;
    int half = lane >> 5;
    int l32 = lane & 31;
    float4 acc = make_float4(0.f, 0.f, 0.f, 0.f);
    if (deg <= 64) {
#pragma unroll 2
        for (int j = beg; j < end; j += 2) {
            int idx = j + half;
            int t = (idx < end) ? (idx - beg) : (deg - 1);
            int s = __shfl(c_reg, t);
            float w = __shfl(e_reg, t);
            if (idx >= end) w = 0.f;
            float4 hv = h4[(size_t)s * 32 + l32];
            acc.x = fmaf(w, hv.x, acc.x);
            acc.y = fmaf(w, hv.y, acc.y);
            acc.z = fmaf(w, hv.z, acc.z);
            acc.w = fmaf(w, hv.w, acc.w);
        }
    } else {
#pragma unroll 2
        for (int j = beg; j < end; j += 2) {
            int idx = j + half;
            int ii = (idx < end) ? idx : (end - 1);
            int s = col[ii];
            float w = (idx < end) ? wbuf[ii] : 0.f;
            float4 hv = h4[(size_t)s * 32 + l32];
            acc.x = fmaf(w, hv.x, acc.x);
            acc.y = fmaf(w, hv.y, acc.y);
            acc.z = fmaf(w, hv.z, acc.z);
            acc.w = fmaf(w, hv.w, acc.w);
        }
    }
    acc.x += __shfl_xor(acc.x, 32);
    acc.y += __shfl_xor(acc.y, 32);
    acc.z += __shfl_xor(acc.z, 32);
    acc.w += __shfl_xor(acc.w, 32);

    if (half == 0) {
        float inv = 1.f / den;
        float4 bb = ((const float4*)bias)[l32];
        float4 o;
        o.x = fmaf(acc.x, inv, bb.x); o.x = o.x > 0.f ? o.x : 0.f;
        o.y = fmaf(acc.y, inv, bb.y); o.y = o.y > 0.f ? o.y : 0.f;
        o.z = fmaf(acc.z, inv, bb.z); o.z = o.z > 0.f ? o.z : 0.f;
        o.w = fmaf(acc.w, inv, bb.w); o.w = o.w > 0.f ? o.w : 0.f;
        ((float4*)out)[(size_t)node * 32 + l32] = o;
    }
}

// ---------- graph boundaries via binary search on sorted batch ----------
__global__ void k_gptr(const int* __restrict__ batch, int* __restrict__ gptr, int n, int G) {
    int g = threadIdx.x;
    if (g > G) return;
    if (g == G) { gptr[G] = n; return; }
    int lo = 0, hi = n;
    while (lo < hi) {
        int mid = (lo + hi) >> 1;
        if (batch[mid] < g) lo = mid + 1; else hi = mid;
    }
    gptr[g] = lo;
}

// ---------- mean pool over contiguous row range (no atomics) ----------
__global__ void k_pool_seq(const float* __restrict__ x, const int* __restrict__ gptr,
                           float* __restrict__ pooled) {
    int g = blockIdx.x;
    int t = threadIdx.x;            // 0..255
    int ch = t & (HD - 1);
    int half = t >> 7;
    int beg = gptr[g], end = gptr[g + 1];
    float acc = 0.f;
    for (int r = beg + half; r < end; r += 2) acc += x[r * HD + ch];
    __shared__ float red[2][HD];
    red[half][ch] = acc;
    __syncthreads();
    if (t < HD) {
        float cnt = (float)(end - beg);
        cnt = cnt < 1.f ? 1.f : cnt;
        pooled[g * HD + t] = (red[0][t] + red[1][t]) / cnt;
    }
}

// ---------- doc embedding: relu(doc @ W_doc + b_doc) ----------
__global__ void k_doc(const float* __restrict__ doc, const float* __restrict__ Wd,
                      const float* __restrict__ bd, float* __restrict__ emb) {
    int g = blockIdx.x;
    int t = threadIdx.x;            // 0..127
    __shared__ float ds[DDOC];
    for (int k = t; k < DDOC; k += HD) ds[k] = doc[g * DDOC + k];
    __syncthreads();
    float acc = bd[t];
    for (int k = 0; k < DDOC; ++k) acc += ds[k] * Wd[k * HD + t];
    emb[g * HD + t] = acc > 0.f ? acc : 0.f;
}

// ---------- heads ----------
__global__ void k_head(const float* __restrict__ pooled, const float* __restrict__ emb,
                       const float* __restrict__ Wt, const float* __restrict__ bt,
                       const float* __restrict__ Wm, const float* __restrict__ bm,
                       float* __restrict__ out_task, float* __restrict__ out_time) {
    int g = blockIdx.x;
    int t = threadIdx.x;            // 0..63
    __shared__ float z[2 * HD];
    for (int k = t; k < HD; k += 64) {
        z[k] = pooled[g * HD + k];
        z[HD + k] = emb[g * HD + k];
    }
    __syncthreads();
    if (t < TOUT) {
        float acc = bt[t];
        for (int k = 0; k < 2 * HD; ++k) acc += z[k] * Wt[k * TOUT + t];
        out_task[g * TOUT + t] = acc;
    } else if (t == TOUT) {
        float acc = bm[0];
        for (int k = 0; k < 2 * HD; ++k) acc += z[k] * Wm[k];
        out_time[g] = acc;
    }
}

extern "C" void kernel_launch(void* const* d_in, const int* in_sizes, int n_in,
                              void* d_out, int out_size, void* d_ws, size_t ws_size,
                              hipStream_t stream) {
    const float* x0    = (const float*)d_in[0];
    const int*   ei    = (const int*)d_in[1];
    const int*   batch = (const int*)d_in[2];
    const float* doc   = (const float*)d_in[3];
    const float* W[3]   = {(const float*)d_in[4],  (const float*)d_in[8],  (const float*)d_in[12]};
    const float* a_s[3] = {(const float*)d_in[5],  (const float*)d_in[9],  (const float*)d_in[13]};
    const float* a_d[3] = {(const float*)d_in[6],  (const float*)d_in[10], (const float*)d_in[14]};
    const float* b[3]   = {(const float*)d_in[7],  (const float*)d_in[11], (const float*)d_in[15]};
    const float* Wdoc  = (const float*)d_in[16];
    const float* bdoc  = (const float*)d_in[17];
    const float* Wtask = (const float*)d_in[18];
    const float* btask = (const float*)d_in[19];
    const float* Wtime = (const float*)d_in[20];
    const float* btime = (const float*)d_in[21];

    const int N    = in_sizes[2];
    const int E    = in_sizes[1] / 2;
    const int Etot = E + N;
    const int G    = in_sizes[3] / DDOC;

    // workspace layout
    float* ws = (float*)d_ws;
    float* A      = ws; ws += (size_t)N * HD;   // layer output / next input
    float* Hb     = ws; ws += (size_t)N * HD;   // h = x @ W
    float* alp_s  = ws; ws += N;
    float* alp_d  = ws; ws += N;
    float* wbuf   = ws; ws += Etot;             // fallback softmax weights (deg>64)
    float* pooled = ws; ws += (size_t)G * HD;
    float* emb    = ws; ws += (size_t)G * HD;
    int* deg    = (int*)ws; ws += N;
    int* cursor = (int*)ws; ws += N;
    int* ptr    = (int*)ws; ws += N + 1;
    int* gptr   = (int*)ws; ws += G + 1;
    int* bsum   = (int*)ws; ws += SCANB;
    int* col    = (int*)ws; ws += Etot;

    float* out_task = (float*)d_out;
    float* out_time = out_task + (size_t)G * TOUT;

    const int thr = 256;
    const int nBlocks = (N + thr - 1) / thr;
    const int eBlocks = (Etot + thr - 1) / thr;
    const int sBlocks = (N + SCANB - 1) / SCANB;   // 118 <= SCANB

    // ---- build CSR (dst-sorted adjacency), reused by all 3 layers ----
    k_zero_int<<<nBlocks, thr, 0, stream>>>(deg, N);
    k_hist<<<eBlocks, thr, 0, stream>>>(ei, E, Etot, deg);
    k_scan_part<<<sBlocks, SCANB, 0, stream>>>(deg, bsum, N);
    k_scan_bsum<<<1, SCANB, 0, stream>>>(bsum, sBlocks);
    k_scan_final<<<sBlocks, SCANB, 0, stream>>>(deg, bsum, ptr, cursor, N, Etot);
    k_fill<<<eBlocks, thr, 0, stream>>>(ei, E, Etot, cursor, col);

    // ---- graph boundaries ----
    k_gptr<<<1, G + 1, 0, stream>>>(batch, gptr, N, G);

    // ---- 3 GAT layers ----
    const float* xin = x0;
    for (int l = 0; l < 3; ++l) {
        k_gemm_alpha<<<(N + RB - 1) / RB, thr, 0, stream>>>(xin, W[l], a_s[l], a_d[l],
                                                            Hb, alp_s, alp_d, N);
        k_gat_gather<<<(N + 3) / 4, thr, 0, stream>>>(ptr, col, Hb, alp_s, alp_d, b[l],
                                                      wbuf, A, N);
        xin = A;
    }

    // ---- global mean pool (contiguous segments, no atomics) ----
    k_pool_seq<<<G, thr, 0, stream>>>(A, gptr, pooled);

    // ---- doc embedding + heads ----
    k_doc<<<G, HD, 0, stream>>>(doc, Wdoc, bdoc, emb);
    k_head<<<G, 64, 0, stream>>>(pooled, emb, Wtask, btask, Wtime, btime,
                                 out_task, out_time);
}

// Round 6
// 360.232 us; speedup vs baseline: 4.0098x; 1.1385x over previous
//
#include <hip/hip_runtime.h>

#define HD 128          // hidden dim (== DIN)
#define DDOC 512
#define TOUT 32
#define RB 16           // rows per block in gemm
#define SCANB 256
#define PROWS 64        // rows per block in pooling
constexpr float NEG_SLOPE = 0.2f;

// ---------- zero ----------
__global__ void k_zero_int(int* __restrict__ p, int n) {
    int i = blockIdx.x * blockDim.x + threadIdx.x;
    if (i < n) p[i] = 0;
}
__global__ void k_zero(float* __restrict__ p, int n) {
    int i = blockIdx.x * blockDim.x + threadIdx.x;
    if (i < n) p[i] = 0.f;
}

// ---------- tiled GEMM + fused alpha: h = x@W, alpha = h.a ----------
__global__ void k_gemm_alpha(const float* __restrict__ x, const float* __restrict__ W,
                             const float* __restrict__ av_s, const float* __restrict__ av_d,
                             float* __restrict__ h, float* __restrict__ alp_s,
                             float* __restrict__ alp_d, int n) {
    int row0 = blockIdx.x * RB;
    int t = threadIdx.x;            // 0..255
    int c = t & (HD - 1);
    int rg = t >> 7;                // 0: rows 0-7, 1: rows 8-15

    __shared__ float xs[RB][HD];
    for (int i = t; i < RB * HD; i += 256) {
        int r = i >> 7, k = i & (HD - 1);
        int row = row0 + r;
        xs[r][k] = (row < n) ? x[row * HD + k] : 0.f;
    }
    __syncthreads();

    float acc[8] = {0.f, 0.f, 0.f, 0.f, 0.f, 0.f, 0.f, 0.f};
    for (int k = 0; k < HD; ++k) {
        float w = W[k * HD + c];
#pragma unroll
        for (int r = 0; r < 8; ++r) acc[r] = fmaf(xs[rg * 8 + r][k], w, acc[r]);
    }
#pragma unroll
    for (int r = 0; r < 8; ++r) {
        int row = row0 + rg * 8 + r;
        if (row < n) h[row * HD + c] = acc[r];
    }

    float as = av_s[c], ad = av_d[c];
    __shared__ float redS[4][8], redD[4][8];
    int wave = t >> 6, lane = t & 63;
#pragma unroll
    for (int r = 0; r < 8; ++r) {
        float vs = acc[r] * as;
        float vd = acc[r] * ad;
#pragma unroll
        for (int off = 32; off > 0; off >>= 1) {
            vs += __shfl_xor(vs, off);
            vd += __shfl_xor(vd, off);
        }
        if (lane == 0) { redS[wave][r] = vs; redD[wave][r] = vd; }
    }
    __syncthreads();
    if (t < RB) {
        int w0 = (t < 8) ? 0 : 2;
        int rr = t & 7;
        int row = row0 + t;
        if (row < n) {
            alp_s[row] = redS[w0][rr] + redS[w0 + 1][rr];
            alp_d[row] = redD[w0][rr] + redD[w0 + 1][rr];
        }
    }
}

// ---------- CSR build ----------
__global__ void k_hist(const int* __restrict__ ei, int E, int Etot, int* __restrict__ deg) {
    int i = blockIdx.x * blockDim.x + threadIdx.x;
    if (i >= Etot) return;
    int d = (i < E) ? ei[E + i] : (i - E);
    atomicAdd(&deg[d], 1);
}

// ---------- 3-phase device-wide exclusive scan of deg -> ptr/cursor ----------
__global__ void k_scan_part(const int* __restrict__ deg, int* __restrict__ bsum, int n) {
    int t = threadIdx.x;
    int i = blockIdx.x * SCANB + t;
    int v = (i < n) ? deg[i] : 0;
#pragma unroll
    for (int off = 32; off > 0; off >>= 1) v += __shfl_xor(v, off);
    __shared__ int red[4];
    if ((t & 63) == 0) red[t >> 6] = v;
    __syncthreads();
    if (t == 0) bsum[blockIdx.x] = red[0] + red[1] + red[2] + red[3];
}

__global__ void k_scan_bsum(int* __restrict__ bsum, int nb) {
    __shared__ int part[SCANB];
    int t = threadIdx.x;
    int v = (t < nb) ? bsum[t] : 0;
    part[t] = v;
    __syncthreads();
    for (int off = 1; off < SCANB; off <<= 1) {
        int u = (t >= off) ? part[t - off] : 0;
        __syncthreads();
        part[t] += u;
        __syncthreads();
    }
    if (t < nb) bsum[t] = part[t] - v;   // exclusive
}

__global__ void k_scan_final(const int* __restrict__ deg, const int* __restrict__ bsum,
                             int* __restrict__ ptr, int* __restrict__ cursor,
                             int n, int total) {
    __shared__ int part[SCANB];
    int t = threadIdx.x;
    int i = blockIdx.x * SCANB + t;
    int v = (i < n) ? deg[i] : 0;
    part[t] = v;
    __syncthreads();
    for (int off = 1; off < SCANB; off <<= 1) {
        int u = (t >= off) ? part[t - off] : 0;
        __syncthreads();
        part[t] += u;
        __syncthreads();
    }
    if (i < n) {
        int excl = bsum[blockIdx.x] + part[t] - v;
        ptr[i] = excl;
        cursor[i] = excl;
    }
    if (i == n - 1) ptr[n] = total;
}

__global__ void k_fill(const int* __restrict__ ei, int E, int Etot,
                       int* __restrict__ cursor, int* __restrict__ col) {
    int i = blockIdx.x * blockDim.x + threadIdx.x;
    if (i >= Etot) return;
    int s, d;
    if (i < E) { s = ei[i]; d = ei[E + i]; } else { s = d = i - E; }
    col[atomicAdd(&cursor[d], 1)] = s;
}

// ---------- fused GAT aggregation ----------
__global__ void k_gat_gather(const int* __restrict__ ptr, const int* __restrict__ col,
                             const float* __restrict__ h,
                             const float* __restrict__ alp_s, const float* __restrict__ alp_d,
                             const float* __restrict__ bias, float* __restrict__ wbuf,
                             float* __restrict__ out, int n) {
    int node = blockIdx.x * 4 + (threadIdx.x >> 6);
    if (node >= n) return;
    int lane = threadIdx.x & 63;
    int beg = ptr[node], end = ptr[node + 1];
    int deg = end - beg;
    float ad = alp_d[node];

    // ---- phase A: e, wave-max, exp, denom ----
    float m = -3.4e38f;
    float e_reg = 0.f;
    int   c_reg = 0;
    if (deg <= 64) {
        if (lane < deg) {
            int s = col[beg + lane];
            c_reg = s;
            float e = alp_s[s] + ad;
            e = e > 0.f ? e : NEG_SLOPE * e;
            e_reg = e;
            m = e;
        }
    } else {
        for (int j = beg + lane; j < end; j += 64) {
            int s = col[j];
            float e = alp_s[s] + ad;
            e = e > 0.f ? e : NEG_SLOPE * e;
            wbuf[j] = e;
            m = fmaxf(m, e);
        }
    }
#pragma unroll
    for (int off = 32; off > 0; off >>= 1) m = fmaxf(m, __shfl_xor(m, off));

    float den = 0.f;
    if (deg <= 64) {
        float ee = (lane < deg) ? __expf(e_reg - m) : 0.f;
        e_reg = ee;
        den = ee;
    } else {
        for (int j = beg + lane; j < end; j += 64) {
            float ee = __expf(wbuf[j] - m);
            wbuf[j] = ee;
            den += ee;
        }
    }
#pragma unroll
    for (int off = 32; off > 0; off >>= 1) den += __shfl_xor(den, off);

    // ---- phase B: weighted aggregation ----
    const float4* __restrict__ h4 = (const float4*)h;
    int half = lane >> 5;
    int l32 = lane & 31;
    float4 acc = make_float4(0.f, 0.f, 0.f, 0.f);
    if (deg <= 64) {
#pragma unroll 2
        for (int j = beg; j < end; j += 2) {
            int idx = j + half;
            int t = (idx < end) ? (idx - beg) : (deg - 1);
            int s = __shfl(c_reg, t);
            float w = __shfl(e_reg, t);
            if (idx >= end) w = 0.f;
            float4 hv = h4[(size_t)s * 32 + l32];
            acc.x = fmaf(w, hv.x, acc.x);
            acc.y = fmaf(w, hv.y, acc.y);
            acc.z = fmaf(w, hv.z, acc.z);
            acc.w = fmaf(w, hv.w, acc.w);
        }
    } else {
#pragma unroll 2
        for (int j = beg; j < end; j += 2) {
            int idx = j + half;
            int ii = (idx < end) ? idx : (end - 1);
            int s = col[ii];
            float w = (idx < end) ? wbuf[ii] : 0.f;
            float4 hv = h4[(size_t)s * 32 + l32];
            acc.x = fmaf(w, hv.x, acc.x);
            acc.y = fmaf(w, hv.y, acc.y);
            acc.z = fmaf(w, hv.z, acc.z);
            acc.w = fmaf(w, hv.w, acc.w);
        }
    }
    acc.x += __shfl_xor(acc.x, 32);
    acc.y += __shfl_xor(acc.y, 32);
    acc.z += __shfl_xor(acc.z, 32);
    acc.w += __shfl_xor(acc.w, 32);

    if (half == 0) {
        float inv = 1.f / den;
        float4 bb = ((const float4*)bias)[l32];
        float4 o;
        o.x = fmaf(acc.x, inv, bb.x); o.x = o.x > 0.f ? o.x : 0.f;
        o.y = fmaf(acc.y, inv, bb.y); o.y = o.y > 0.f ? o.y : 0.f;
        o.z = fmaf(acc.z, inv, bb.z); o.z = o.z > 0.f ? o.z : 0.f;
        o.w = fmaf(acc.w, inv, bb.w); o.w = o.w > 0.f ? o.w : 0.f;
        ((float4*)out)[(size_t)node * 32 + l32] = o;
    }
}

// ---------- graph boundaries via binary search on sorted batch ----------
__global__ void k_gptr(const int* __restrict__ batch, int* __restrict__ gptr, int n, int G) {
    int g = threadIdx.x;
    if (g > G) return;
    if (g == G) { gptr[G] = n; return; }
    int lo = 0, hi = n;
    while (lo < hi) {
        int mid = (lo + hi) >> 1;
        if (batch[mid] < g) lo = mid + 1; else hi = mid;
    }
    gptr[g] = lo;
}

// ---------- parallel mean pool: chunked partial sums, flush on graph change ----------
__global__ void k_pool_part(const float* __restrict__ x, const int* __restrict__ batch,
                            float* __restrict__ pooled, int n) {
    int r0 = blockIdx.x * PROWS;
    int t = threadIdx.x;            // 0..255
    int ch = t & (HD - 1);
    int rg = t >> 7;                // 0,1
    int rend = r0 + PROWS; if (rend > n) rend = n;
    float acc = 0.f;
    int curg = -1;
    for (int r = r0 + rg; r < rend; r += 2) {
        int g = batch[r];
        if (g != curg) {
            if (curg >= 0) atomicAdd(&pooled[curg * HD + ch], acc);
            curg = g;
            acc = 0.f;
        }
        acc += x[r * HD + ch];
    }
    if (curg >= 0) atomicAdd(&pooled[curg * HD + ch], acc);
}

__global__ void k_pool_div(float* __restrict__ pooled, const int* __restrict__ gptr, int total) {
    int i = blockIdx.x * blockDim.x + threadIdx.x;
    if (i >= total) return;
    int g = i >> 7;                 // /HD
    float cnt = (float)(gptr[g + 1] - gptr[g]);
    cnt = cnt < 1.f ? 1.f : cnt;
    pooled[i] /= cnt;
}

// ---------- doc embedding: relu(doc @ W_doc + b_doc) ----------
__global__ void k_doc(const float* __restrict__ doc, const float* __restrict__ Wd,
                      const float* __restrict__ bd, float* __restrict__ emb) {
    int g = blockIdx.x;
    int t = threadIdx.x;            // 0..127
    __shared__ float ds[DDOC];
    for (int k = t; k < DDOC; k += HD) ds[k] = doc[g * DDOC + k];
    __syncthreads();
    float acc = bd[t];
    for (int k = 0; k < DDOC; ++k) acc += ds[k] * Wd[k * HD + t];
    emb[g * HD + t] = acc > 0.f ? acc : 0.f;
}

// ---------- heads ----------
__global__ void k_head(const float* __restrict__ pooled, const float* __restrict__ emb,
                       const float* __restrict__ Wt, const float* __restrict__ bt,
                       const float* __restrict__ Wm, const float* __restrict__ bm,
                       float* __restrict__ out_task, float* __restrict__ out_time) {
    int g = blockIdx.x;
    int t = threadIdx.x;            // 0..63
    __shared__ float z[2 * HD];
    for (int k = t; k < HD; k += 64) {
        z[k] = pooled[g * HD + k];
        z[HD + k] = emb[g * HD + k];
    }
    __syncthreads();
    if (t < TOUT) {
        float acc = bt[t];
        for (int k = 0; k < 2 * HD; ++k) acc += z[k] * Wt[k * TOUT + t];
        out_task[g * TOUT + t] = acc;
    } else if (t == TOUT) {
        float acc = bm[0];
        for (int k = 0; k < 2 * HD; ++k) acc += z[k] * Wm[k];
        out_time[g] = acc;
    }
}

extern "C" void kernel_launch(void* const* d_in, const int* in_sizes, int n_in,
                              void* d_out, int out_size, void* d_ws, size_t ws_size,
                              hipStream_t stream) {
    const float* x0    = (const float*)d_in[0];
    const int*   ei    = (const int*)d_in[1];
    const int*   batch = (const int*)d_in[2];
    const float* doc   = (const float*)d_in[3];
    const float* W[3]   = {(const float*)d_in[4],  (const float*)d_in[8],  (const float*)d_in[12]};
    const float* a_s[3] = {(const float*)d_in[5],  (const float*)d_in[9],  (const float*)d_in[13]};
    const float* a_d[3] = {(const float*)d_in[6],  (const float*)d_in[10], (const float*)d_in[14]};
    const float* b[3]   = {(const float*)d_in[7],  (const float*)d_in[11], (const float*)d_in[15]};
    const float* Wdoc  = (const float*)d_in[16];
    const float* bdoc  = (const float*)d_in[17];
    const float* Wtask = (const float*)d_in[18];
    const float* btask = (const float*)d_in[19];
    const float* Wtime = (const float*)d_in[20];
    const float* btime = (const float*)d_in[21];

    const int N    = in_sizes[2];
    const int E    = in_sizes[1] / 2;
    const int Etot = E + N;
    const int G    = in_sizes[3] / DDOC;

    // workspace layout
    float* ws = (float*)d_ws;
    float* A      = ws; ws += (size_t)N * HD;   // layer output / next input
    float* Hb     = ws; ws += (size_t)N * HD;   // h = x @ W
    float* alp_s  = ws; ws += N;
    float* alp_d  = ws; ws += N;
    float* wbuf   = ws; ws += Etot;             // fallback softmax weights (deg>64)
    float* pooled = ws; ws += (size_t)G * HD;
    float* emb    = ws; ws += (size_t)G * HD;
    int* deg    = (int*)ws; ws += N;
    int* cursor = (int*)ws; ws += N;
    int* ptr    = (int*)ws; ws += N + 1;
    int* gptr   = (int*)ws; ws += G + 1;
    int* bsum   = (int*)ws; ws += SCANB;
    int* col    = (int*)ws; ws += Etot;

    float* out_task = (float*)d_out;
    float* out_time = out_task + (size_t)G * TOUT;

    const int thr = 256;
    const int nBlocks = (N + thr - 1) / thr;
    const int eBlocks = (Etot + thr - 1) / thr;
    const int sBlocks = (N + SCANB - 1) / SCANB;   // 118 <= SCANB

    // ---- build CSR (dst-sorted adjacency), reused by all 3 layers ----
    k_zero_int<<<nBlocks, thr, 0, stream>>>(deg, N);
    k_hist<<<eBlocks, thr, 0, stream>>>(ei, E, Etot, deg);
    k_scan_part<<<sBlocks, SCANB, 0, stream>>>(deg, bsum, N);
    k_scan_bsum<<<1, SCANB, 0, stream>>>(bsum, sBlocks);
    k_scan_final<<<sBlocks, SCANB, 0, stream>>>(deg, bsum, ptr, cursor, N, Etot);
    k_fill<<<eBlocks, thr, 0, stream>>>(ei, E, Etot, cursor, col);

    // ---- graph boundaries ----
    k_gptr<<<1, G + 1, 0, stream>>>(batch, gptr, N, G);

    // ---- 3 GAT layers ----
    const float* xin = x0;
    for (int l = 0; l < 3; ++l) {
        k_gemm_alpha<<<(N + RB - 1) / RB, thr, 0, stream>>>(xin, W[l], a_s[l], a_d[l],
                                                            Hb, alp_s, alp_d, N);
        k_gat_gather<<<(N + 3) / 4, thr, 0, stream>>>(ptr, col, Hb, alp_s, alp_d, b[l],
                                                      wbuf, A, N);
        xin = A;
    }

    // ---- global mean pool (parallel partials + divide) ----
    k_zero<<<(G * HD + thr - 1) / thr, thr, 0, stream>>>(pooled, G * HD);
    k_pool_part<<<(N + PROWS - 1) / PROWS, thr, 0, stream>>>(A, batch, pooled, N);
    k_pool_div<<<(G * HD + thr - 1) / thr, thr, 0, stream>>>(pooled, gptr, G * HD);

    // ---- doc embedding + heads ----
    k_doc<<<G, HD, 0, stream>>>(doc, Wdoc, bdoc, emb);
    k_head<<<G, 64, 0, stream>>>(pooled, emb, Wtask, btask, Wtime, btime,
                                 out_task, out_time);
}

// Round 7
// 322.136 us; speedup vs baseline: 4.4840x; 1.1183x over previous
//
#include <hip/hip_runtime.h>

#define HD 128          // hidden dim (== DIN)
#define DDOC 512
#define TOUT 32
#define RB 16           // rows per block in gemm
#define SCANB 256
#define PROWS 64        // rows per block in pooling
constexpr float NEG_SLOPE = 0.2f;

// ---------- bf16 helpers ----------
__device__ __forceinline__ unsigned short f2bf(float f) {
    unsigned int b = __float_as_uint(f);
    b += 0x7fffu + ((b >> 16) & 1u);     // round-to-nearest-even
    return (unsigned short)(b >> 16);
}
__device__ __forceinline__ float bflo2f(unsigned int u) { return __uint_as_float(u << 16); }
__device__ __forceinline__ float bfhi2f(unsigned int u) { return __uint_as_float(u & 0xffff0000u); }

// ---------- zero ----------
__global__ void k_zero_int(int* __restrict__ p, int n) {
    int i = blockIdx.x * blockDim.x + threadIdx.x;
    if (i < n) p[i] = 0;
}
__global__ void k_zero(float* __restrict__ p, int n) {
    int i = blockIdx.x * blockDim.x + threadIdx.x;
    if (i < n) p[i] = 0.f;
}

// ---------- tiled GEMM + fused alpha: h = x@W (bf16 out), alpha = h.a (fp32) ----------
__global__ void k_gemm_alpha(const float* __restrict__ x, const float* __restrict__ W,
                             const float* __restrict__ av_s, const float* __restrict__ av_d,
                             unsigned short* __restrict__ h, float* __restrict__ alp_s,
                             float* __restrict__ alp_d, int n) {
    int row0 = blockIdx.x * RB;
    int t = threadIdx.x;            // 0..255
    int c = t & (HD - 1);
    int rg = t >> 7;                // 0: rows 0-7, 1: rows 8-15

    __shared__ float xs[RB][HD];
    for (int i = t; i < RB * HD; i += 256) {
        int r = i >> 7, k = i & (HD - 1);
        int row = row0 + r;
        xs[r][k] = (row < n) ? x[row * HD + k] : 0.f;
    }
    __syncthreads();

    float acc[8] = {0.f, 0.f, 0.f, 0.f, 0.f, 0.f, 0.f, 0.f};
    for (int k = 0; k < HD; ++k) {
        float w = W[k * HD + c];
#pragma unroll
        for (int r = 0; r < 8; ++r) acc[r] = fmaf(xs[rg * 8 + r][k], w, acc[r]);
    }
#pragma unroll
    for (int r = 0; r < 8; ++r) {
        int row = row0 + rg * 8 + r;
        if (row < n) h[row * HD + c] = f2bf(acc[r]);
    }

    float as = av_s[c], ad = av_d[c];
    __shared__ float redS[4][8], redD[4][8];
    int wave = t >> 6, lane = t & 63;
#pragma unroll
    for (int r = 0; r < 8; ++r) {
        float vs = acc[r] * as;
        float vd = acc[r] * ad;
#pragma unroll
        for (int off = 32; off > 0; off >>= 1) {
            vs += __shfl_xor(vs, off);
            vd += __shfl_xor(vd, off);
        }
        if (lane == 0) { redS[wave][r] = vs; redD[wave][r] = vd; }
    }
    __syncthreads();
    if (t < RB) {
        int w0 = (t < 8) ? 0 : 2;
        int rr = t & 7;
        int row = row0 + t;
        if (row < n) {
            alp_s[row] = redS[w0][rr] + redS[w0 + 1][rr];
            alp_d[row] = redD[w0][rr] + redD[w0 + 1][rr];
        }
    }
}

// ---------- CSR build ----------
__global__ void k_hist(const int* __restrict__ ei, int E, int Etot, int* __restrict__ deg) {
    int i = blockIdx.x * blockDim.x + threadIdx.x;
    if (i >= Etot) return;
    int d = (i < E) ? ei[E + i] : (i - E);
    atomicAdd(&deg[d], 1);
}

// ---------- 3-phase device-wide exclusive scan of deg -> ptr/cursor ----------
__global__ void k_scan_part(const int* __restrict__ deg, int* __restrict__ bsum, int n) {
    int t = threadIdx.x;
    int i = blockIdx.x * SCANB + t;
    int v = (i < n) ? deg[i] : 0;
#pragma unroll
    for (int off = 32; off > 0; off >>= 1) v += __shfl_xor(v, off);
    __shared__ int red[4];
    if ((t & 63) == 0) red[t >> 6] = v;
    __syncthreads();
    if (t == 0) bsum[blockIdx.x] = red[0] + red[1] + red[2] + red[3];
}

__global__ void k_scan_bsum(int* __restrict__ bsum, int nb) {
    __shared__ int part[SCANB];
    int t = threadIdx.x;
    int v = (t < nb) ? bsum[t] : 0;
    part[t] = v;
    __syncthreads();
    for (int off = 1; off < SCANB; off <<= 1) {
        int u = (t >= off) ? part[t - off] : 0;
        __syncthreads();
        part[t] += u;
        __syncthreads();
    }
    if (t < nb) bsum[t] = part[t] - v;   // exclusive
}

__global__ void k_scan_final(const int* __restrict__ deg, const int* __restrict__ bsum,
                             int* __restrict__ ptr, int* __restrict__ cursor,
                             int n, int total) {
    __shared__ int part[SCANB];
    int t = threadIdx.x;
    int i = blockIdx.x * SCANB + t;
    int v = (i < n) ? deg[i] : 0;
    part[t] = v;
    __syncthreads();
    for (int off = 1; off < SCANB; off <<= 1) {
        int u = (t >= off) ? part[t - off] : 0;
        __syncthreads();
        part[t] += u;
        __syncthreads();
    }
    if (i < n) {
        int excl = bsum[blockIdx.x] + part[t] - v;
        ptr[i] = excl;
        cursor[i] = excl;
    }
    if (i == n - 1) ptr[n] = total;
}

__global__ void k_fill(const int* __restrict__ ei, int E, int Etot,
                       int* __restrict__ cursor, int* __restrict__ col) {
    int i = blockIdx.x * blockDim.x + threadIdx.x;
    if (i >= Etot) return;
    int s, d;
    if (i < E) { s = ei[i]; d = ei[E + i]; } else { s = d = i - E; }
    col[atomicAdd(&cursor[d], 1)] = s;
}

// ---------- fused GAT aggregation (h in bf16) ----------
__global__ void k_gat_gather(const int* __restrict__ ptr, const int* __restrict__ col,
                             const unsigned short* __restrict__ h,
                             const float* __restrict__ alp_s, const float* __restrict__ alp_d,
                             const float* __restrict__ bias, float* __restrict__ wbuf,
                             float* __restrict__ out, int n) {
    int node = blockIdx.x * 4 + (threadIdx.x >> 6);
    if (node >= n) return;
    int lane = threadIdx.x & 63;
    int beg = ptr[node], end = ptr[node + 1];
    int deg = end - beg;
    float ad = alp_d[node];

    // ---- phase A: e, wave-max, exp, denom ----
    float m = -3.4e38f;
    float e_reg = 0.f;
    int   c_reg = 0;
    if (deg <= 64) {
        if (lane < deg) {
            int s = col[beg + lane];
            c_reg = s;
            float e = alp_s[s] + ad;
            e = e > 0.f ? e : NEG_SLOPE * e;
            e_reg = e;
            m = e;
        }
    } else {
        for (int j = beg + lane; j < end; j += 64) {
            int s = col[j];
            float e = alp_s[s] + ad;
            e = e > 0.f ? e : NEG_SLOPE * e;
            wbuf[j] = e;
            m = fmaxf(m, e);
        }
    }
#pragma unroll
    for (int off = 32; off > 0; off >>= 1) m = fmaxf(m, __shfl_xor(m, off));

    float den = 0.f;
    if (deg <= 64) {
        float ee = (lane < deg) ? __expf(e_reg - m) : 0.f;
        e_reg = ee;
        den = ee;
    } else {
        for (int j = beg + lane; j < end; j += 64) {
            float ee = __expf(wbuf[j] - m);
            wbuf[j] = ee;
            den += ee;
        }
    }
#pragma unroll
    for (int off = 32; off > 0; off >>= 1) den += __shfl_xor(den, off);

    // ---- phase B: weighted aggregation; lane owns channels 4*l32..4*l32+3 ----
    const uint2* __restrict__ h2 = (const uint2*)h;
    int half = lane >> 5;
    int l32 = lane & 31;
    float4 acc = make_float4(0.f, 0.f, 0.f, 0.f);
    if (deg <= 64) {
#pragma unroll 2
        for (int j = beg; j < end; j += 2) {
            int idx = j + half;
            int t = (idx < end) ? (idx - beg) : (deg - 1);
            int s = __shfl(c_reg, t);
            float w = __shfl(e_reg, t);
            if (idx >= end) w = 0.f;
            uint2 hv = h2[(size_t)s * 32 + l32];
            acc.x = fmaf(w, bflo2f(hv.x), acc.x);
            acc.y = fmaf(w, bfhi2f(hv.x), acc.y);
            acc.z = fmaf(w, bflo2f(hv.y), acc.z);
            acc.w = fmaf(w, bfhi2f(hv.y), acc.w);
        }
    } else {
#pragma unroll 2
        for (int j = beg; j < end; j += 2) {
            int idx = j + half;
            int ii = (idx < end) ? idx : (end - 1);
            int s = col[ii];
            float w = (idx < end) ? wbuf[ii] : 0.f;
            uint2 hv = h2[(size_t)s * 32 + l32];
            acc.x = fmaf(w, bflo2f(hv.x), acc.x);
            acc.y = fmaf(w, bfhi2f(hv.x), acc.y);
            acc.z = fmaf(w, bflo2f(hv.y), acc.z);
            acc.w = fmaf(w, bfhi2f(hv.y), acc.w);
        }
    }
    acc.x += __shfl_xor(acc.x, 32);
    acc.y += __shfl_xor(acc.y, 32);
    acc.z += __shfl_xor(acc.z, 32);
    acc.w += __shfl_xor(acc.w, 32);

    if (half == 0) {
        float inv = 1.f / den;
        float4 bb = ((const float4*)bias)[l32];
        float4 o;
        o.x = fmaf(acc.x, inv, bb.x); o.x = o.x > 0.f ? o.x : 0.f;
        o.y = fmaf(acc.y, inv, bb.y); o.y = o.y > 0.f ? o.y : 0.f;
        o.z = fmaf(acc.z, inv, bb.z); o.z = o.z > 0.f ? o.z : 0.f;
        o.w = fmaf(acc.w, inv, bb.w); o.w = o.w > 0.f ? o.w : 0.f;
        ((float4*)out)[(size_t)node * 32 + l32] = o;
    }
}

// ---------- graph boundaries via binary search on sorted batch ----------
__global__ void k_gptr(const int* __restrict__ batch, int* __restrict__ gptr, int n, int G) {
    int g = threadIdx.x;
    if (g > G) return;
    if (g == G) { gptr[G] = n; return; }
    int lo = 0, hi = n;
    while (lo < hi) {
        int mid = (lo + hi) >> 1;
        if (batch[mid] < g) lo = mid + 1; else hi = mid;
    }
    gptr[g] = lo;
}

// ---------- parallel mean pool: chunked partial sums, flush on graph change ----------
__global__ void k_pool_part(const float* __restrict__ x, const int* __restrict__ batch,
                            float* __restrict__ pooled, int n) {
    int r0 = blockIdx.x * PROWS;
    int t = threadIdx.x;            // 0..255
    int ch = t & (HD - 1);
    int rg = t >> 7;                // 0,1
    int rend = r0 + PROWS; if (rend > n) rend = n;
    float acc = 0.f;
    int curg = -1;
    for (int r = r0 + rg; r < rend; r += 2) {
        int g = batch[r];
        if (g != curg) {
            if (curg >= 0) atomicAdd(&pooled[curg * HD + ch], acc);
            curg = g;
            acc = 0.f;
        }
        acc += x[r * HD + ch];
    }
    if (curg >= 0) atomicAdd(&pooled[curg * HD + ch], acc);
}

__global__ void k_pool_div(float* __restrict__ pooled, const int* __restrict__ gptr, int total) {
    int i = blockIdx.x * blockDim.x + threadIdx.x;
    if (i >= total) return;
    int g = i >> 7;                 // /HD
    float cnt = (float)(gptr[g + 1] - gptr[g]);
    cnt = cnt < 1.f ? 1.f : cnt;
    pooled[i] /= cnt;
}

// ---------- doc embedding: relu(doc @ W_doc + b_doc) ----------
__global__ void k_doc(const float* __restrict__ doc, const float* __restrict__ Wd,
                      const float* __restrict__ bd, float* __restrict__ emb) {
    int g = blockIdx.x;
    int t = threadIdx.x;            // 0..127
    __shared__ float ds[DDOC];
    for (int k = t; k < DDOC; k += HD) ds[k] = doc[g * DDOC + k];
    __syncthreads();
    float acc = bd[t];
    for (int k = 0; k < DDOC; ++k) acc += ds[k] * Wd[k * HD + t];
    emb[g * HD + t] = acc > 0.f ? acc : 0.f;
}

// ---------- heads ----------
__global__ void k_head(const float* __restrict__ pooled, const float* __restrict__ emb,
                       const float* __restrict__ Wt, const float* __restrict__ bt,
                       const float* __restrict__ Wm, const float* __restrict__ bm,
                       float* __restrict__ out_task, float* __restrict__ out_time) {
    int g = blockIdx.x;
    int t = threadIdx.x;            // 0..63
    __shared__ float z[2 * HD];
    for (int k = t; k < HD; k += 64) {
        z[k] = pooled[g * HD + k];
        z[HD + k] = emb[g * HD + k];
    }
    __syncthreads();
    if (t < TOUT) {
        float acc = bt[t];
        for (int k = 0; k < 2 * HD; ++k) acc += z[k] * Wt[k * TOUT + t];
        out_task[g * TOUT + t] = acc;
    } else if (t == TOUT) {
        float acc = bm[0];
        for (int k = 0; k < 2 * HD; ++k) acc += z[k] * Wm[k];
        out_time[g] = acc;
    }
}

extern "C" void kernel_launch(void* const* d_in, const int* in_sizes, int n_in,
                              void* d_out, int out_size, void* d_ws, size_t ws_size,
                              hipStream_t stream) {
    const float* x0    = (const float*)d_in[0];
    const int*   ei    = (const int*)d_in[1];
    const int*   batch = (const int*)d_in[2];
    const float* doc   = (const float*)d_in[3];
    const float* W[3]   = {(const float*)d_in[4],  (const float*)d_in[8],  (const float*)d_in[12]};
    const float* a_s[3] = {(const float*)d_in[5],  (const float*)d_in[9],  (const float*)d_in[13]};
    const float* a_d[3] = {(const float*)d_in[6],  (const float*)d_in[10], (const float*)d_in[14]};
    const float* b[3]   = {(const float*)d_in[7],  (const float*)d_in[11], (const float*)d_in[15]};
    const float* Wdoc  = (const float*)d_in[16];
    const float* bdoc  = (const float*)d_in[17];
    const float* Wtask = (const float*)d_in[18];
    const float* btask = (const float*)d_in[19];
    const float* Wtime = (const float*)d_in[20];
    const float* btime = (const float*)d_in[21];

    const int N    = in_sizes[2];
    const int E    = in_sizes[1] / 2;
    const int Etot = E + N;
    const int G    = in_sizes[3] / DDOC;

    // workspace layout
    float* ws = (float*)d_ws;
    float* A      = ws; ws += (size_t)N * HD;   // layer output / next input (fp32)
    unsigned short* Hb = (unsigned short*)ws; ws += (size_t)N * HD / 2;  // h (bf16)
    float* alp_s  = ws; ws += N;
    float* alp_d  = ws; ws += N;
    float* wbuf   = ws; ws += Etot;             // fallback softmax weights (deg>64)
    float* pooled = ws; ws += (size_t)G * HD;
    float* emb    = ws; ws += (size_t)G * HD;
    int* deg    = (int*)ws; ws += N;
    int* cursor = (int*)ws; ws += N;
    int* ptr    = (int*)ws; ws += N + 1;
    int* gptr   = (int*)ws; ws += G + 1;
    int* bsum   = (int*)ws; ws += SCANB;
    int* col    = (int*)ws; ws += Etot;

    float* out_task = (float*)d_out;
    float* out_time = out_task + (size_t)G * TOUT;

    const int thr = 256;
    const int nBlocks = (N + thr - 1) / thr;
    const int eBlocks = (Etot + thr - 1) / thr;
    const int sBlocks = (N + SCANB - 1) / SCANB;   // 118 <= SCANB

    // ---- build CSR (dst-sorted adjacency), reused by all 3 layers ----
    k_zero_int<<<nBlocks, thr, 0, stream>>>(deg, N);
    k_hist<<<eBlocks, thr, 0, stream>>>(ei, E, Etot, deg);
    k_scan_part<<<sBlocks, SCANB, 0, stream>>>(deg, bsum, N);
    k_scan_bsum<<<1, SCANB, 0, stream>>>(bsum, sBlocks);
    k_scan_final<<<sBlocks, SCANB, 0, stream>>>(deg, bsum, ptr, cursor, N, Etot);
    k_fill<<<eBlocks, thr, 0, stream>>>(ei, E, Etot, cursor, col);

    // ---- graph boundaries ----
    k_gptr<<<1, G + 1, 0, stream>>>(batch, gptr, N, G);

    // ---- 3 GAT layers ----
    const float* xin = x0;
    for (int l = 0; l < 3; ++l) {
        k_gemm_alpha<<<(N + RB - 1) / RB, thr, 0, stream>>>(xin, W[l], a_s[l], a_d[l],
                                                            Hb, alp_s, alp_d, N);
        k_gat_gather<<<(N + 3) / 4, thr, 0, stream>>>(ptr, col, Hb, alp_s, alp_d, b[l],
                                                      wbuf, A, N);
        xin = A;
    }

    // ---- global mean pool (parallel partials + divide) ----
    k_zero<<<(G * HD + thr - 1) / thr, thr, 0, stream>>>(pooled, G * HD);
    k_pool_part<<<(N + PROWS - 1) / PROWS, thr, 0, stream>>>(A, batch, pooled, N);
    k_pool_div<<<(G * HD + thr - 1) / thr, thr, 0, stream>>>(pooled, gptr, G * HD);

    // ---- doc embedding + heads ----
    k_doc<<<G, HD, 0, stream>>>(doc, Wdoc, bdoc, emb);
    k_head<<<G, 64, 0, stream>>>(pooled, emb, Wtask, btask, Wtime, btime,
                                 out_task, out_time);
}

// Round 8
// 276.297 us; speedup vs baseline: 5.2279x; 1.1659x over previous
//
#include <hip/hip_runtime.h>

#define HD 128          // hidden dim (== DIN)
#define DDOC 512
#define TOUT 32
#define RB 16           // rows per block in gemm
#define SCANB 256
#define PROWS 64        // rows per block in pooling
constexpr float NEG_SLOPE = 0.2f;

// ---------- bf16 helpers ----------
__device__ __forceinline__ unsigned short f2bf(float f) {
    unsigned int b = __float_as_uint(f);
    b += 0x7fffu + ((b >> 16) & 1u);     // round-to-nearest-even
    return (unsigned short)(b >> 16);
}
__device__ __forceinline__ float bflo2f(unsigned int u) { return __uint_as_float(u << 16); }
__device__ __forceinline__ float bfhi2f(unsigned int u) { return __uint_as_float(u & 0xffff0000u); }

// ---------- init: zero deg + pooled ----------
__global__ void k_init(int* __restrict__ deg, float* __restrict__ pooled, int n, int np) {
    int i = blockIdx.x * blockDim.x + threadIdx.x;
    if (i < n) deg[i] = 0;
    if (i < np) pooled[i] = 0.f;
}

// ---------- tiled GEMM + fused alpha: h = x@W (bf16 out), alpha = h.a (fp32) ----------
__global__ void k_gemm_alpha(const float* __restrict__ x, const float* __restrict__ W,
                             const float* __restrict__ av_s, const float* __restrict__ av_d,
                             unsigned short* __restrict__ h, float* __restrict__ alp_s,
                             float* __restrict__ alp_d, int n) {
    int row0 = blockIdx.x * RB;
    int t = threadIdx.x;            // 0..255
    int c = t & (HD - 1);
    int rg = t >> 7;                // 0: rows 0-7, 1: rows 8-15

    __shared__ float xs[RB][HD];
    for (int i = t; i < RB * HD; i += 256) {
        int r = i >> 7, k = i & (HD - 1);
        int row = row0 + r;
        xs[r][k] = (row < n) ? x[row * HD + k] : 0.f;
    }
    __syncthreads();

    float acc[8] = {0.f, 0.f, 0.f, 0.f, 0.f, 0.f, 0.f, 0.f};
    for (int k = 0; k < HD; ++k) {
        float w = W[k * HD + c];
#pragma unroll
        for (int r = 0; r < 8; ++r) acc[r] = fmaf(xs[rg * 8 + r][k], w, acc[r]);
    }
#pragma unroll
    for (int r = 0; r < 8; ++r) {
        int row = row0 + rg * 8 + r;
        if (row < n) h[row * HD + c] = f2bf(acc[r]);
    }

    float as = av_s[c], ad = av_d[c];
    __shared__ float redS[4][8], redD[4][8];
    int wave = t >> 6, lane = t & 63;
#pragma unroll
    for (int r = 0; r < 8; ++r) {
        float vs = acc[r] * as;
        float vd = acc[r] * ad;
#pragma unroll
        for (int off = 32; off > 0; off >>= 1) {
            vs += __shfl_xor(vs, off);
            vd += __shfl_xor(vd, off);
        }
        if (lane == 0) { redS[wave][r] = vs; redD[wave][r] = vd; }
    }
    __syncthreads();
    if (t < RB) {
        int w0 = (t < 8) ? 0 : 2;
        int rr = t & 7;
        int row = row0 + t;
        if (row < n) {
            alp_s[row] = redS[w0][rr] + redS[w0 + 1][rr];
            alp_d[row] = redD[w0][rr] + redD[w0 + 1][rr];
        }
    }
}

// ---------- CSR build: hist captures per-edge rank (one atomic pass total) ----------
__global__ void k_hist(const int* __restrict__ ei, int E, int Etot,
                       int* __restrict__ deg, int* __restrict__ rank) {
    int i = blockIdx.x * blockDim.x + threadIdx.x;
    if (i >= Etot) return;
    int d = (i < E) ? ei[E + i] : (i - E);
    rank[i] = atomicAdd(&deg[d], 1);
}

// ---------- 3-phase device-wide exclusive scan of deg -> ptr ----------
__global__ void k_scan_part(const int* __restrict__ deg, int* __restrict__ bsum, int n) {
    int t = threadIdx.x;
    int i = blockIdx.x * SCANB + t;
    int v = (i < n) ? deg[i] : 0;
#pragma unroll
    for (int off = 32; off > 0; off >>= 1) v += __shfl_xor(v, off);
    __shared__ int red[4];
    if ((t & 63) == 0) red[t >> 6] = v;
    __syncthreads();
    if (t == 0) bsum[blockIdx.x] = red[0] + red[1] + red[2] + red[3];
}

__global__ void k_scan_bsum(int* __restrict__ bsum, int nb) {
    __shared__ int part[SCANB];
    int t = threadIdx.x;
    int v = (t < nb) ? bsum[t] : 0;
    part[t] = v;
    __syncthreads();
    for (int off = 1; off < SCANB; off <<= 1) {
        int u = (t >= off) ? part[t - off] : 0;
        __syncthreads();
        part[t] += u;
        __syncthreads();
    }
    if (t < nb) bsum[t] = part[t] - v;   // exclusive
}

__global__ void k_scan_final(const int* __restrict__ deg, const int* __restrict__ bsum,
                             int* __restrict__ ptr, int n, int total) {
    __shared__ int part[SCANB];
    int t = threadIdx.x;
    int i = blockIdx.x * SCANB + t;
    int v = (i < n) ? deg[i] : 0;
    part[t] = v;
    __syncthreads();
    for (int off = 1; off < SCANB; off <<= 1) {
        int u = (t >= off) ? part[t - off] : 0;
        __syncthreads();
        part[t] += u;
        __syncthreads();
    }
    if (i < n) ptr[i] = bsum[blockIdx.x] + part[t] - v;
    if (i == n - 1) ptr[n] = total;
}

// ---------- fill: atomic-free, pos = ptr[d] + rank[i] ----------
__global__ void k_fill(const int* __restrict__ ei, int E, int Etot,
                       const int* __restrict__ ptr, const int* __restrict__ rank,
                       int* __restrict__ col) {
    int i = blockIdx.x * blockDim.x + threadIdx.x;
    if (i >= Etot) return;
    int s, d;
    if (i < E) { s = ei[i]; d = ei[E + i]; } else { s = d = i - E; }
    col[ptr[d] + rank[i]] = s;
}

// ---------- fused GAT aggregation (h in bf16, 4 edges/iter quarter-waves) ----------
__global__ void k_gat_gather(const int* __restrict__ ptr, const int* __restrict__ col,
                             const unsigned short* __restrict__ h,
                             const float* __restrict__ alp_s, const float* __restrict__ alp_d,
                             const float* __restrict__ bias, float* __restrict__ wbuf,
                             float* __restrict__ out, int n) {
    int node = blockIdx.x * 4 + (threadIdx.x >> 6);
    if (node >= n) return;
    int lane = threadIdx.x & 63;
    int beg = ptr[node], end = ptr[node + 1];
    int deg = end - beg;
    float ad = alp_d[node];

    // ---- phase A: e, wave-max, exp, denom ----
    float m = -3.4e38f;
    float e_reg = 0.f;
    int   c_reg = 0;
    if (deg <= 64) {
        if (lane < deg) {
            int s = col[beg + lane];
            c_reg = s;
            float e = alp_s[s] + ad;
            e = e > 0.f ? e : NEG_SLOPE * e;
            e_reg = e;
            m = e;
        }
    } else {
        for (int j = beg + lane; j < end; j += 64) {
            int s = col[j];
            float e = alp_s[s] + ad;
            e = e > 0.f ? e : NEG_SLOPE * e;
            wbuf[j] = e;
            m = fmaxf(m, e);
        }
    }
#pragma unroll
    for (int off = 32; off > 0; off >>= 1) m = fmaxf(m, __shfl_xor(m, off));

    float den = 0.f;
    if (deg <= 64) {
        float ee = (lane < deg) ? __expf(e_reg - m) : 0.f;
        e_reg = ee;
        den = ee;
    } else {
        for (int j = beg + lane; j < end; j += 64) {
            float ee = __expf(wbuf[j] - m);
            wbuf[j] = ee;
            den += ee;
        }
    }
#pragma unroll
    for (int off = 32; off > 0; off >>= 1) den += __shfl_xor(den, off);

    // ---- phase B: 4 edges/iter; quarter-wave (16 lanes) per edge.
    // lane owns 8 channels: l16*8 .. l16*8+7 (uint4 = 8 bf16 = 16 B)
    const uint4* __restrict__ h4 = (const uint4*)h;
    int q = lane >> 4;              // 0..3: which edge of the group
    int l16 = lane & 15;
    float accA[4] = {0.f, 0.f, 0.f, 0.f};
    float accB[4] = {0.f, 0.f, 0.f, 0.f};
    if (deg <= 64) {
        for (int j = beg; j < end; j += 4) {
            int idx = j + q;
            int t = (idx < end) ? (idx - beg) : (deg - 1);
            int s = __shfl(c_reg, t);
            float w = __shfl(e_reg, t);
            if (idx >= end) w = 0.f;
            uint4 hv = h4[(size_t)s * 16 + l16];
            accA[0] = fmaf(w, bflo2f(hv.x), accA[0]);
            accA[1] = fmaf(w, bfhi2f(hv.x), accA[1]);
            accA[2] = fmaf(w, bflo2f(hv.y), accA[2]);
            accA[3] = fmaf(w, bfhi2f(hv.y), accA[3]);
            accB[0] = fmaf(w, bflo2f(hv.z), accB[0]);
            accB[1] = fmaf(w, bfhi2f(hv.z), accB[1]);
            accB[2] = fmaf(w, bflo2f(hv.w), accB[2]);
            accB[3] = fmaf(w, bfhi2f(hv.w), accB[3]);
        }
    } else {
        for (int j = beg; j < end; j += 4) {
            int idx = j + q;
            int ii = (idx < end) ? idx : (end - 1);
            int s = col[ii];
            float w = (idx < end) ? wbuf[ii] : 0.f;
            uint4 hv = h4[(size_t)s * 16 + l16];
            accA[0] = fmaf(w, bflo2f(hv.x), accA[0]);
            accA[1] = fmaf(w, bfhi2f(hv.x), accA[1]);
            accA[2] = fmaf(w, bflo2f(hv.y), accA[2]);
            accA[3] = fmaf(w, bfhi2f(hv.y), accA[3]);
            accB[0] = fmaf(w, bflo2f(hv.z), accB[0]);
            accB[1] = fmaf(w, bfhi2f(hv.z), accB[1]);
            accB[2] = fmaf(w, bflo2f(hv.w), accB[2]);
            accB[3] = fmaf(w, bfhi2f(hv.w), accB[3]);
        }
    }
    // combine the four quarter-wave partial sums
#pragma unroll
    for (int r = 0; r < 4; ++r) {
        accA[r] += __shfl_xor(accA[r], 16);
        accA[r] += __shfl_xor(accA[r], 32);
        accB[r] += __shfl_xor(accB[r], 16);
        accB[r] += __shfl_xor(accB[r], 32);
    }

    if (q == 0) {
        float inv = 1.f / den;
        const float4* b4 = (const float4*)bias;
        float4 bb0 = b4[l16 * 2];
        float4 bb1 = b4[l16 * 2 + 1];
        float4 o0, o1;
        o0.x = fmaf(accA[0], inv, bb0.x); o0.x = o0.x > 0.f ? o0.x : 0.f;
        o0.y = fmaf(accA[1], inv, bb0.y); o0.y = o0.y > 0.f ? o0.y : 0.f;
        o0.z = fmaf(accA[2], inv, bb0.z); o0.z = o0.z > 0.f ? o0.z : 0.f;
        o0.w = fmaf(accA[3], inv, bb0.w); o0.w = o0.w > 0.f ? o0.w : 0.f;
        o1.x = fmaf(accB[0], inv, bb1.x); o1.x = o1.x > 0.f ? o1.x : 0.f;
        o1.y = fmaf(accB[1], inv, bb1.y); o1.y = o1.y > 0.f ? o1.y : 0.f;
        o1.z = fmaf(accB[2], inv, bb1.z); o1.z = o1.z > 0.f ? o1.z : 0.f;
        o1.w = fmaf(accB[3], inv, bb1.w); o1.w = o1.w > 0.f ? o1.w : 0.f;
        float4* o4 = (float4*)out;
        o4[(size_t)node * 32 + l16 * 2]     = o0;
        o4[(size_t)node * 32 + l16 * 2 + 1] = o1;
    }
}

// ---------- graph boundaries via binary search on sorted batch ----------
__global__ void k_gptr(const int* __restrict__ batch, int* __restrict__ gptr, int n, int G) {
    int g = threadIdx.x;
    if (g > G) return;
    if (g == G) { gptr[G] = n; return; }
    int lo = 0, hi = n;
    while (lo < hi) {
        int mid = (lo + hi) >> 1;
        if (batch[mid] < g) lo = mid + 1; else hi = mid;
    }
    gptr[g] = lo;
}

// ---------- parallel mean pool: chunked partial sums, flush on graph change ----------
__global__ void k_pool_part(const float* __restrict__ x, const int* __restrict__ batch,
                            float* __restrict__ pooled, int n) {
    int r0 = blockIdx.x * PROWS;
    int t = threadIdx.x;            // 0..255
    int ch = t & (HD - 1);
    int rg = t >> 7;                // 0,1
    int rend = r0 + PROWS; if (rend > n) rend = n;
    float acc = 0.f;
    int curg = -1;
    for (int r = r0 + rg; r < rend; r += 2) {
        int g = batch[r];
        if (g != curg) {
            if (curg >= 0) atomicAdd(&pooled[curg * HD + ch], acc);
            curg = g;
            acc = 0.f;
        }
        acc += x[r * HD + ch];
    }
    if (curg >= 0) atomicAdd(&pooled[curg * HD + ch], acc);
}

__global__ void k_pool_div(float* __restrict__ pooled, const int* __restrict__ gptr, int total) {
    int i = blockIdx.x * blockDim.x + threadIdx.x;
    if (i >= total) return;
    int g = i >> 7;                 // /HD
    float cnt = (float)(gptr[g + 1] - gptr[g]);
    cnt = cnt < 1.f ? 1.f : cnt;
    pooled[i] /= cnt;
}

// ---------- doc embedding: relu(doc @ W_doc + b_doc) ----------
__global__ void k_doc(const float* __restrict__ doc, const float* __restrict__ Wd,
                      const float* __restrict__ bd, float* __restrict__ emb) {
    int g = blockIdx.x;
    int t = threadIdx.x;            // 0..127
    __shared__ float ds[DDOC];
    for (int k = t; k < DDOC; k += HD) ds[k] = doc[g * DDOC + k];
    __syncthreads();
    float acc = bd[t];
    for (int k = 0; k < DDOC; ++k) acc += ds[k] * Wd[k * HD + t];
    emb[g * HD + t] = acc > 0.f ? acc : 0.f;
}

// ---------- heads ----------
__global__ void k_head(const float* __restrict__ pooled, const float* __restrict__ emb,
                       const float* __restrict__ Wt, const float* __restrict__ bt,
                       const float* __restrict__ Wm, const float* __restrict__ bm,
                       float* __restrict__ out_task, float* __restrict__ out_time) {
    int g = blockIdx.x;
    int t = threadIdx.x;            // 0..63
    __shared__ float z[2 * HD];
    for (int k = t; k < HD; k += 64) {
        z[k] = pooled[g * HD + k];
        z[HD + k] = emb[g * HD + k];
    }
    __syncthreads();
    if (t < TOUT) {
        float acc = bt[t];
        for (int k = 0; k < 2 * HD; ++k) acc += z[k] * Wt[k * TOUT + t];
        out_task[g * TOUT + t] = acc;
    } else if (t == TOUT) {
        float acc = bm[0];
        for (int k = 0; k < 2 * HD; ++k) acc += z[k] * Wm[k];
        out_time[g] = acc;
    }
}

extern "C" void kernel_launch(void* const* d_in, const int* in_sizes, int n_in,
                              void* d_out, int out_size, void* d_ws, size_t ws_size,
                              hipStream_t stream) {
    const float* x0    = (const float*)d_in[0];
    const int*   ei    = (const int*)d_in[1];
    const int*   batch = (const int*)d_in[2];
    const float* doc   = (const float*)d_in[3];
    const float* W[3]   = {(const float*)d_in[4],  (const float*)d_in[8],  (const float*)d_in[12]};
    const float* a_s[3] = {(const float*)d_in[5],  (const float*)d_in[9],  (const float*)d_in[13]};
    const float* a_d[3] = {(const float*)d_in[6],  (const float*)d_in[10], (const float*)d_in[14]};
    const float* b[3]   = {(const float*)d_in[7],  (const float*)d_in[11], (const float*)d_in[15]};
    const float* Wdoc  = (const float*)d_in[16];
    const float* bdoc  = (const float*)d_in[17];
    const float* Wtask = (const float*)d_in[18];
    const float* btask = (const float*)d_in[19];
    const float* Wtime = (const float*)d_in[20];
    const float* btime = (const float*)d_in[21];

    const int N    = in_sizes[2];
    const int E    = in_sizes[1] / 2;
    const int Etot = E + N;
    const int G    = in_sizes[3] / DDOC;

    // workspace layout
    float* ws = (float*)d_ws;
    float* A      = ws; ws += (size_t)N * HD;   // layer output / next input (fp32)
    unsigned short* Hb = (unsigned short*)ws; ws += (size_t)N * HD / 2;  // h (bf16)
    float* alp_s  = ws; ws += N;
    float* alp_d  = ws; ws += N;
    float* wbuf   = ws; ws += Etot;             // fallback softmax weights (deg>64)
    float* pooled = ws; ws += (size_t)G * HD;
    float* emb    = ws; ws += (size_t)G * HD;
    int* deg    = (int*)ws; ws += N;
    int* rank   = (int*)ws; ws += Etot;
    int* ptr    = (int*)ws; ws += N + 1;
    int* gptr   = (int*)ws; ws += G + 1;
    int* bsum   = (int*)ws; ws += SCANB;
    int* col    = (int*)ws; ws += Etot;

    float* out_task = (float*)d_out;
    float* out_time = out_task + (size_t)G * TOUT;

    const int thr = 256;
    const int nBlocks = (N + thr - 1) / thr;
    const int eBlocks = (Etot + thr - 1) / thr;
    const int sBlocks = (N + SCANB - 1) / SCANB;   // 118 <= SCANB

    // ---- build CSR (dst-sorted adjacency), reused by all 3 layers ----
    k_init<<<nBlocks, thr, 0, stream>>>(deg, pooled, N, G * HD);
    k_hist<<<eBlocks, thr, 0, stream>>>(ei, E, Etot, deg, rank);
    k_scan_part<<<sBlocks, SCANB, 0, stream>>>(deg, bsum, N);
    k_scan_bsum<<<1, SCANB, 0, stream>>>(bsum, sBlocks);
    k_scan_final<<<sBlocks, SCANB, 0, stream>>>(deg, bsum, ptr, N, Etot);
    k_fill<<<eBlocks, thr, 0, stream>>>(ei, E, Etot, ptr, rank, col);

    // ---- graph boundaries ----
    k_gptr<<<1, G + 1, 0, stream>>>(batch, gptr, N, G);

    // ---- 3 GAT layers ----
    const float* xin = x0;
    for (int l = 0; l < 3; ++l) {
        k_gemm_alpha<<<(N + RB - 1) / RB, thr, 0, stream>>>(xin, W[l], a_s[l], a_d[l],
                                                            Hb, alp_s, alp_d, N);
        k_gat_gather<<<(N + 3) / 4, thr, 0, stream>>>(ptr, col, Hb, alp_s, alp_d, b[l],
                                                      wbuf, A, N);
        xin = A;
    }

    // ---- global mean pool (parallel partials + divide) ----
    k_pool_part<<<(N + PROWS - 1) / PROWS, thr, 0, stream>>>(A, batch, pooled, N);
    k_pool_div<<<(G * HD + thr - 1) / thr, thr, 0, stream>>>(pooled, gptr, G * HD);

    // ---- doc embedding + heads ----
    k_doc<<<G, HD, 0, stream>>>(doc, Wdoc, bdoc, emb);
    k_head<<<G, 64, 0, stream>>>(pooled, emb, Wtask, btask, Wtime, btime,
                                 out_task, out_time);
}